// Round 2
// baseline (5403.715 us; speedup 1.0000x reference)
//
#include <hip/hip_runtime.h>

#define T_SEQ 64
#define NV 4096
#define NE 65536
#define CIN 128
#define H2 512
#define HO 256
#define NEG_FLT (-3.402823466e38f)

typedef unsigned short u16;
typedef __bf16 bf16x8 __attribute__((ext_vector_type(8)));
typedef float f32x4 __attribute__((ext_vector_type(4)));

__device__ __forceinline__ u16 f2bf(float f){
  unsigned u = __float_as_uint(f);
  unsigned r = (u + 0x7FFFu + ((u >> 16) & 1u)) >> 16;
  return (u16)r;
}
__device__ __forceinline__ float bf2f(u16 h){
  return __uint_as_float(((unsigned)h) << 16);
}

// ---------------- workspace layout ----------------
struct Lay {
  size_t z, c, zn, cn, Bt1h, Bt1l, Bt2h, Bt2l, cnt, fill, rowptr, deginv, csr,
         aggh, aggl, xh, xl, hh, hl, mh, partial, total;
};
static Lay mk_layout(int tc){
  Lay L; size_t o = 0;
  auto tk = [&](size_t b){ size_t p = o; o += ((b + 255) & ~(size_t)255); return p; };
  L.z       = tk((size_t)T_SEQ * HO * 4);
  L.c       = tk((size_t)T_SEQ * HO * 4);
  L.zn      = tk((size_t)T_SEQ * 4);
  L.cn      = tk((size_t)T_SEQ * 4);
  L.Bt1h    = tk((size_t)512 * 256 * 2);
  L.Bt1l    = tk((size_t)512 * 256 * 2);
  L.Bt2h    = tk((size_t)512 * 512 * 2);
  L.Bt2l    = tk((size_t)512 * 512 * 2);
  L.cnt     = tk((size_t)tc * NV * 4);
  L.fill    = tk((size_t)tc * NV * 4);
  L.rowptr  = tk((size_t)tc * (NV + 1) * 4);
  L.deginv  = tk((size_t)tc * NV * 4);
  L.csr     = tk((size_t)tc * NE * 4);
  L.aggh    = tk((size_t)tc * NV * CIN * 2);
  L.aggl    = tk((size_t)tc * NV * CIN * 2);
  L.xh      = tk((size_t)tc * NV * CIN * 2);
  L.xl      = tk((size_t)tc * NV * CIN * 2);
  L.hh      = tk((size_t)tc * NV * H2 * 2);
  L.hl      = tk((size_t)tc * NV * H2 * 2);
  L.mh      = tk((size_t)tc * NV * H2 * 4);
  L.partial = tk((size_t)tc * 128 * HO * 4);
  L.total = o; return L;
}

// ---------------- small kernels ----------------
__global__ void k_init_out(float* out){
  int i = threadIdx.x;
  if (i < 2) out[i] = 0.0f;
}

// B transposed + bf16-split: Bt1[n][k] (512x256), Bt2[n][k] (512x512)
__global__ void k_prep_Bt(const float* __restrict__ W1l, const float* __restrict__ W1r,
                          const float* __restrict__ W2l, const float* __restrict__ W2r,
                          u16* __restrict__ Bt1h, u16* __restrict__ Bt1l,
                          u16* __restrict__ Bt2h, u16* __restrict__ Bt2l){
  int i = blockIdx.x * 256 + threadIdx.x;
  if (i < 512 * 256){
    int n = i >> 8, k = i & 255;
    float v = (k < 128) ? W1l[k * 512 + n] : W1r[(k - 128) * 512 + n];
    u16 h = f2bf(v);
    Bt1h[i] = h; Bt1l[i] = f2bf(v - bf2f(h));
  } else {
    int j = i - 512 * 256;
    if (j < 512 * 512){
      int n = j >> 9, k = j & 511;
      float v = (n < 256) ? W2l[k * 256 + n] : W2r[k * 256 + (n - 256)];
      u16 h = f2bf(v);
      Bt2h[j] = h; Bt2l[j] = f2bf(v - bf2f(h));
    }
  }
}

__global__ void k_zero(int* p, int n){
  int i = blockIdx.x * 256 + threadIdx.x;
  if (i < n) p[i] = 0;
}

__global__ void k_count(const int* __restrict__ ei, int t0, int tc, int* __restrict__ cnt){
  int i = blockIdx.x * 256 + threadIdx.x;
  if (i >= tc * NE) return;
  int tl = i >> 16, e = i & (NE - 1);
  int dst = ei[(size_t)(t0 + tl) * 2 * NE + NE + e];
  atomicAdd(&cnt[tl * NV + dst], 1);
}

__global__ void k_scan(const int* __restrict__ cnt, int* __restrict__ rowptr,
                       float* __restrict__ deginv){
  int tl = blockIdx.x, tid = threadIdx.x;
  __shared__ int s[256];
  int vals[16]; int sum = 0;
  const int* cb = cnt + tl * NV + tid * 16;
  #pragma unroll
  for (int i = 0; i < 16; i++){ vals[i] = cb[i]; sum += vals[i]; }
  s[tid] = sum; __syncthreads();
  for (int off = 1; off < 256; off <<= 1){
    int v = (tid >= off) ? s[tid - off] : 0;
    __syncthreads();
    s[tid] += v;
    __syncthreads();
  }
  int ex = s[tid] - sum;
  int* rp = rowptr + tl * (NV + 1) + tid * 16;
  float* dv = deginv + tl * NV + tid * 16;
  #pragma unroll
  for (int i = 0; i < 16; i++){
    rp[i] = ex; ex += vals[i];
    int d = vals[i] < 1 ? 1 : vals[i];
    dv[i] = 1.0f / (float)d;
  }
  if (tid == 255) rowptr[tl * (NV + 1) + NV] = ex;
}

__global__ void k_fill(const int* __restrict__ ei, int t0, int tc,
                       const int* __restrict__ rowptr, int* __restrict__ fill,
                       int* __restrict__ csr){
  int i = blockIdx.x * 256 + threadIdx.x;
  if (i >= tc * NE) return;
  int tl = i >> 16, e = i & (NE - 1);
  const int* eit = ei + (size_t)(t0 + tl) * 2 * NE;
  int src = eit[e], dst = eit[NE + e];
  int pos = atomicAdd(&fill[tl * NV + dst], 1);
  csr[tl * NE + rowptr[tl * (NV + 1) + dst] + pos] = src;
}

// x slice -> bf16 hi/lo planes
__global__ void k_xsplit(const float* __restrict__ xs, int n4,
                         u16* __restrict__ xh, u16* __restrict__ xl){
  int i = blockIdx.x * 256 + threadIdx.x;
  if (i >= n4) return;
  float4 v = ((const float4*)xs)[i];
  u16 h0 = f2bf(v.x), h1 = f2bf(v.y), h2 = f2bf(v.z), h3 = f2bf(v.w);
  u16 l0 = f2bf(v.x - bf2f(h0)), l1 = f2bf(v.y - bf2f(h1));
  u16 l2 = f2bf(v.z - bf2f(h2)), l3 = f2bf(v.w - bf2f(h3));
  ushort4 hv; hv.x = h0; hv.y = h1; hv.z = h2; hv.w = h3;
  ushort4 lv; lv.x = l0; lv.y = l1; lv.z = l2; lv.w = l3;
  *(ushort4*)(xh + (size_t)i * 4) = hv;
  *(ushort4*)(xl + (size_t)i * 4) = lv;
}

// conv1 aggregation: one wave per (t, v); lanes cover 128 ch as float2; writes bf16 hi/lo
__global__ __launch_bounds__(256) void k_agg1(const float* __restrict__ x, int t0, int tc,
                       const int* __restrict__ rowptr, const int* __restrict__ csr,
                       const float* __restrict__ deginv,
                       u16* __restrict__ aggh, u16* __restrict__ aggl){
  int w = (blockIdx.x * 256 + threadIdx.x) >> 6;
  int lane = threadIdx.x & 63;
  if (w >= tc * NV) return;
  int tl = w >> 12, v = w & (NV - 1);
  const float2* xt = (const float2*)(x + (size_t)(t0 + tl) * NV * CIN);
  int beg = rowptr[tl * (NV + 1) + v], end = rowptr[tl * (NV + 1) + v + 1];
  const int* cs = csr + tl * NE;
  float ax = 0.f, ay = 0.f;
  for (int j = beg; j < end; j++){
    int s = cs[j];
    float2 xv = xt[(size_t)s * 64 + lane];
    ax += xv.x; ay += xv.y;
  }
  float di = deginv[tl * NV + v];
  float vx = ax * di, vy = ay * di;
  u16 hx = f2bf(vx), hy = f2bf(vy);
  u16 lx = f2bf(vx - bf2f(hx)), ly = f2bf(vy - bf2f(hy));
  ushort2 hv; hv.x = hx; hv.y = hy;
  ushort2 lv; lv.x = lx; lv.y = ly;
  ((ushort2*)aggh)[(size_t)w * 64 + lane] = hv;
  ((ushort2*)aggl)[(size_t)w * 64 + lane] = lv;
}

// ---------------- split-bf16 MFMA GEMM ----------------
// C[M x 512] = A @ B, A = [A0 | A1] split at ksplit (both [M][lda] bf16 hi/lo planes),
// B passed transposed: Bt[512][K] bf16 hi/lo. 3-term split: Ah*Bh + Ah*Bl + Al*Bh.
// 128x128 block, 4 waves (2x2 of 64x64), BK=32, frag-linear LDS, 1 barrier/K-step.
// mode 1: += bias, relu, write bf16 hi/lo planes. mode 0: write fp32.
__global__ __launch_bounds__(256, 2) void k_gemm_mfma(
    const u16* __restrict__ Ah0, const u16* __restrict__ Al0,
    const u16* __restrict__ Ah1, const u16* __restrict__ Al1,
    int ksplit, int lda,
    const u16* __restrict__ Bh, const u16* __restrict__ Bl, int K,
    const float* __restrict__ bias, int mode,
    u16* __restrict__ OutH, u16* __restrict__ OutL, float* __restrict__ OutF)
{
  __shared__ uint4 lds[4096];   // 64 KB: per buf (2048): Ah[0,512) Al[512,1024) Bh[1024,1536) Bl[1536,2048)
  int tid = threadIdx.x;
  int bm = blockIdx.x >> 2, bn = blockIdx.x & 3;
  size_t row0 = (size_t)bm * 128;
  int col0 = bn * 128;
  int lane = tid & 63, wid = tid >> 6;
  int wm = wid >> 1, wn = wid & 1;

  int slot[2];
  #pragma unroll
  for (int q = 0; q < 2; q++){
    int c = tid + q * 256; int rw = c >> 2; int kq = c & 3;
    slot[q] = (rw >> 4) * 64 + ((rw & 15) | (kq << 4));
  }

#define LOAD_TILE(T, RA, RB) do { \
    int k0_ = (T) << 5; \
    _Pragma("unroll") \
    for (int q = 0; q < 2; q++){ \
      int c_ = tid + q * 256; int rw_ = c_ >> 2; int kq_ = c_ & 3; \
      int kabs_ = k0_ + kq_ * 8; \
      const u16* ph_ = Ah0; const u16* pl_ = Al0; int kk_ = kabs_; \
      if (kabs_ >= ksplit){ ph_ = Ah1; pl_ = Al1; kk_ = kabs_ - ksplit; } \
      size_t offA_ = (row0 + rw_) * (size_t)lda + kk_; \
      RA[q]     = *(const uint4*)(ph_ + offA_); \
      RA[q + 2] = *(const uint4*)(pl_ + offA_); \
      size_t offB_ = (size_t)(col0 + rw_) * K + k0_ + kq_ * 8; \
      RB[q]     = *(const uint4*)(Bh + offB_); \
      RB[q + 2] = *(const uint4*)(Bl + offB_); \
    } \
  } while (0)

  f32x4 zv = {0.f, 0.f, 0.f, 0.f};
  f32x4 acc[4][4];
  #pragma unroll
  for (int i = 0; i < 4; i++)
    #pragma unroll
    for (int j = 0; j < 4; j++) acc[i][j] = zv;

  uint4 ra[4], rb[4];
  uint4 na[4] = {}, nb[4] = {};
  LOAD_TILE(0, ra, rb);

  int nt = K >> 5;
  for (int t = 0; t < nt; t++){
    int base = (t & 1) << 11;
    #pragma unroll
    for (int q = 0; q < 2; q++){
      lds[base + slot[q]]        = ra[q];
      lds[base + 512 + slot[q]]  = ra[q + 2];
      lds[base + 1024 + slot[q]] = rb[q];
      lds[base + 1536 + slot[q]] = rb[q + 2];
    }
    __syncthreads();
    if (t + 1 < nt) LOAD_TILE(t + 1, na, nb);
    bf16x8 ah[4], al[4], bh[4], bl[4];
    int abase = base + wm * 256;
    int bbase = base + 1024 + wn * 256;
    #pragma unroll
    for (int f = 0; f < 4; f++){
      ah[f] = __builtin_bit_cast(bf16x8, lds[abase + f * 64 + lane]);
      al[f] = __builtin_bit_cast(bf16x8, lds[abase + 512 + f * 64 + lane]);
      bh[f] = __builtin_bit_cast(bf16x8, lds[bbase + f * 64 + lane]);
      bl[f] = __builtin_bit_cast(bf16x8, lds[bbase + 512 + f * 64 + lane]);
    }
    #pragma unroll
    for (int i = 0; i < 4; i++)
      #pragma unroll
      for (int j = 0; j < 4; j++){
        acc[i][j] = __builtin_amdgcn_mfma_f32_16x16x32_bf16(ah[i], bh[j], acc[i][j], 0, 0, 0);
        acc[i][j] = __builtin_amdgcn_mfma_f32_16x16x32_bf16(ah[i], bl[j], acc[i][j], 0, 0, 0);
        acc[i][j] = __builtin_amdgcn_mfma_f32_16x16x32_bf16(al[i], bh[j], acc[i][j], 0, 0, 0);
      }
    #pragma unroll
    for (int q = 0; q < 4; q++){ ra[q] = na[q]; rb[q] = nb[q]; }
    // no second barrier: next iter writes the other buffer; overwrite of this one
    // is gated by the NEXT __syncthreads(), and every ds_read was consumed by an
    // MFMA (lgkmcnt-waited) before this wave reaches that barrier.
  }
#undef LOAD_TILE

  // epilogue: C/D frag layout col=lane&15, row=(lane>>4)*4+reg
  #pragma unroll
  for (int i = 0; i < 4; i++){
    #pragma unroll
    for (int j = 0; j < 4; j++){
      int col = col0 + wn * 64 + j * 16 + (lane & 15);
      float bv = bias ? bias[col] : 0.f;
      #pragma unroll
      for (int r = 0; r < 4; r++){
        size_t row = row0 + wm * 64 + i * 16 + ((lane >> 4) * 4) + r;
        float v = acc[i][j][r] + bv;
        if (mode == 1){
          v = fmaxf(v, 0.f);
          u16 h = f2bf(v);
          u16 l = f2bf(v - bf2f(h));
          OutH[row * 512 + col] = h;
          OutL[row * 512 + col] = l;
        } else {
          OutF[row * 512 + col] = v;
        }
      }
    }
  }
}

// conv2 aggregation + finalize + per-block partial max-pool (mh fp32 [M][512]).
__global__ __launch_bounds__(256) void k_conv2agg(
    const float* __restrict__ mh, const int* __restrict__ rowptr,
    const int* __restrict__ csr, const float* __restrict__ deginv,
    const float* __restrict__ b2l, float* __restrict__ partial){
  int blk = blockIdx.x;
  int tl = blk >> 7, nb = blk & 127;
  int wid = threadIdx.x >> 6, lane = threadIdx.x & 63;
  const float4* m4 = (const float4*)mh;
  const int* rp = rowptr + tl * (NV + 1);
  const int* cs = csr + tl * NE;
  float4 bb = ((const float4*)b2l)[lane];
  float4 vmax; vmax.x = NEG_FLT; vmax.y = NEG_FLT; vmax.z = NEG_FLT; vmax.w = NEG_FLT;
  int v0 = nb * 32 + wid * 8;
  for (int q = 0; q < 8; q++){
    int v = v0 + q;
    int beg = rp[v], end = rp[v + 1];
    float4 acc; acc.x = 0.f; acc.y = 0.f; acc.z = 0.f; acc.w = 0.f;
    for (int j = beg; j < end; j++){
      int s = cs[j];
      float4 mv = m4[(size_t)(tl * NV + s) * 128 + lane];
      acc.x += mv.x; acc.y += mv.y; acc.z += mv.z; acc.w += mv.w;
    }
    float di = deginv[tl * NV + v];
    float4 hr = m4[(size_t)(tl * NV + v) * 128 + 64 + lane];
    float4 val;
    val.x = acc.x * di + bb.x + hr.x;
    val.y = acc.y * di + bb.y + hr.y;
    val.z = acc.z * di + bb.z + hr.z;
    val.w = acc.w * di + bb.w + hr.w;
    vmax.x = fmaxf(vmax.x, val.x); vmax.y = fmaxf(vmax.y, val.y);
    vmax.z = fmaxf(vmax.z, val.z); vmax.w = fmaxf(vmax.w, val.w);
  }
  __shared__ float4 sm[4][64];
  sm[wid][lane] = vmax;
  __syncthreads();
  if (wid == 0){
    float4 a = sm[0][lane], b = sm[1][lane], c = sm[2][lane], d = sm[3][lane];
    float4 r;
    r.x = fmaxf(fmaxf(a.x, b.x), fmaxf(c.x, d.x));
    r.y = fmaxf(fmaxf(a.y, b.y), fmaxf(c.y, d.y));
    r.z = fmaxf(fmaxf(a.z, b.z), fmaxf(c.z, d.z));
    r.w = fmaxf(fmaxf(a.w, b.w), fmaxf(c.w, d.w));
    ((float4*)partial)[((size_t)(tl * 128 + nb)) * 64 + lane] = r;
  }
}

__global__ void k_pool(const float* __restrict__ partial, int t0, int tc,
                       float* __restrict__ z, float* __restrict__ zn){
  int tl = blockIdx.x, c = threadIdx.x;
  float m = NEG_FLT;
  for (int b = 0; b < 128; b++)
    m = fmaxf(m, partial[((size_t)(tl * 128 + b)) * HO + c]);
  z[(t0 + tl) * HO + c] = m;
  __shared__ float s[256];
  s[c] = m * m; __syncthreads();
  for (int off = 128; off > 0; off >>= 1){
    if (c < off) s[c] += s[c + off];
    __syncthreads();
  }
  if (c == 0) zn[t0 + tl] = sqrtf(s[0]);
}

__global__ void k_gru(const float* __restrict__ z, const float* __restrict__ Wih,
                      const float* __restrict__ bih, const float* __restrict__ bhh,
                      float* __restrict__ c, float* __restrict__ cn, float* __restrict__ out){
  int s0 = blockIdx.x, j = threadIdx.x;
  __shared__ float zs[256];
  __shared__ float ss[256];
  zs[j] = z[s0 * HO + j];
  __syncthreads();
  const float* wr = Wih + (size_t)j * HO;
  const float* wu = Wih + (size_t)(HO + j) * HO;
  const float* wn = Wih + (size_t)(2 * HO + j) * HO;
  float gr = bih[j], gu = bih[HO + j], gn = bih[2 * HO + j];
  for (int k = 0; k < HO; k++){
    float zv = zs[k];
    gr = fmaf(zv, wr[k], gr);
    gu = fmaf(zv, wu[k], gu);
    gn = fmaf(zv, wn[k], gn);
  }
  float r = 1.f / (1.f + expf(-(gr + bhh[j])));
  float u = 1.f / (1.f + expf(-(gu + bhh[HO + j])));
  float n = tanhf(gn + r * bhh[2 * HO + j]);
  float cv = (1.f - u) * n;
  c[s0 * HO + j] = cv;
  if (s0 < 44) out[2 + s0 * HO + j] = cv;
  ss[j] = cv * cv; __syncthreads();
  for (int off = 128; off > 0; off >>= 1){
    if (j < off) ss[j] += ss[j + off];
    __syncthreads();
  }
  if (j == 0) cn[s0] = sqrtf(ss[0]);
}

__global__ void k_cpc(const float* __restrict__ z, const float* __restrict__ c,
                      const float* __restrict__ zn, const float* __restrict__ cn,
                      float* __restrict__ out){
  int tt = blockIdx.x;
  int ts = 8 + tt;
  int tid = threadIdx.x;
  __shared__ float ct[256];
  __shared__ float tot[32];
  ct[tid] = c[ts * HO + tid];
  __syncthreads();
  int g = tid >> 3, r = tid & 7;
  int i = g >> 3, j = g & 7;
  int idx = ts + ((j == 0) ? (i + 1) : (i + j + 10));
  const float* zr = z + idx * HO;
  float s = 0.f;
  for (int k = r; k < HO; k += 8) s = fmaf(zr[k], ct[k], s);
  s += __shfl_down(s, 4, 8);
  s += __shfl_down(s, 2, 8);
  s += __shfl_down(s, 1, 8);
  if (r == 0){
    float den = fmaxf(zn[idx], 1e-8f) * fmaxf(cn[ts], 1e-8f);
    tot[g] = s / den;
  }
  __syncthreads();
  if (tid < 4){
    const float* tr = tot + tid * 8;
    float m = tr[0];
    for (int q = 1; q < 8; q++) m = fmaxf(m, tr[q]);
    float se = 0.f;
    for (int q = 0; q < 8; q++) se += expf(tr[q] - m);
    float lse = m + logf(se);
    float nce = (lse - tr[0]) * (1.0f / 144.0f);
    float corr = (tr[0] == m) ? (1.0f / 144.0f) : 0.f;
    atomicAdd(&out[0], nce);
    atomicAdd(&out[1], corr);
  }
}

// ---------------- launch ----------------
extern "C" void kernel_launch(void* const* d_in, const int* in_sizes, int n_in,
                              void* d_out, int out_size, void* d_ws, size_t ws_size,
                              hipStream_t stream){
  const float* x   = (const float*)d_in[0];
  const int*   ei  = (const int*)  d_in[1];
  const float* W1l = (const float*)d_in[2];
  const float* b1l = (const float*)d_in[3];
  const float* W1r = (const float*)d_in[4];
  const float* W2l = (const float*)d_in[5];
  const float* b2l = (const float*)d_in[6];
  const float* W2r = (const float*)d_in[7];
  const float* Wih = (const float*)d_in[8];
  const float* bih = (const float*)d_in[10];
  const float* bhh = (const float*)d_in[11];
  float* out = (float*)d_out;

  int tc = 64;
  while (tc > 1 && mk_layout(tc).total > ws_size) tc >>= 1;
  Lay L = mk_layout(tc);
  char* w = (char*)d_ws;
  float* zB   = (float*)(w + L.z);
  float* cB   = (float*)(w + L.c);
  float* znB  = (float*)(w + L.zn);
  float* cnB  = (float*)(w + L.cn);
  u16*   Bt1h = (u16*)  (w + L.Bt1h);
  u16*   Bt1l = (u16*)  (w + L.Bt1l);
  u16*   Bt2h = (u16*)  (w + L.Bt2h);
  u16*   Bt2l = (u16*)  (w + L.Bt2l);
  int*   cnt  = (int*)  (w + L.cnt);
  int*   fill = (int*)  (w + L.fill);
  int*   rp   = (int*)  (w + L.rowptr);
  float* dinv = (float*)(w + L.deginv);
  int*   csr  = (int*)  (w + L.csr);
  u16*   aggh = (u16*)  (w + L.aggh);
  u16*   aggl = (u16*)  (w + L.aggl);
  u16*   xh   = (u16*)  (w + L.xh);
  u16*   xl   = (u16*)  (w + L.xl);
  u16*   hh   = (u16*)  (w + L.hh);
  u16*   hl   = (u16*)  (w + L.hl);
  float* mhB  = (float*)(w + L.mh);
  float* part = (float*)(w + L.partial);

  hipLaunchKernelGGL(k_init_out, dim3(1), dim3(64), 0, stream, out);
  hipLaunchKernelGGL(k_prep_Bt, dim3(1536), dim3(256), 0, stream,
                     W1l, W1r, W2l, W2r, Bt1h, Bt1l, Bt2h, Bt2l);

  for (int t0 = 0; t0 < T_SEQ; t0 += tc){
    int nE = tc * NE;
    int M = tc * NV;
    hipLaunchKernelGGL(k_zero, dim3((tc * NV + 255) / 256), dim3(256), 0, stream, cnt, tc * NV);
    hipLaunchKernelGGL(k_zero, dim3((tc * NV + 255) / 256), dim3(256), 0, stream, fill, tc * NV);
    hipLaunchKernelGGL(k_count, dim3((nE + 255) / 256), dim3(256), 0, stream, ei, t0, tc, cnt);
    hipLaunchKernelGGL(k_scan, dim3(tc), dim3(256), 0, stream, cnt, rp, dinv);
    hipLaunchKernelGGL(k_fill, dim3((nE + 255) / 256), dim3(256), 0, stream, ei, t0, tc, rp, fill, csr);
    hipLaunchKernelGGL(k_agg1, dim3(tc * NV / 4), dim3(256), 0, stream,
                       x, t0, tc, rp, csr, dinv, aggh, aggl);
    int n4 = tc * NV * CIN / 4;
    hipLaunchKernelGGL(k_xsplit, dim3((n4 + 255) / 256), dim3(256), 0, stream,
                       x + (size_t)t0 * NV * CIN, n4, xh, xl);
    // conv1: h = relu([agg | x] @ B1 + b1l) -> bf16 hi/lo planes
    hipLaunchKernelGGL(k_gemm_mfma, dim3((M / 128) * 4), dim3(256), 0, stream,
                       aggh, aggl, xh, xl, 128, CIN,
                       Bt1h, Bt1l, 256, b1l, 1, hh, hl, (float*)nullptr);
    // conv2: mh = h @ B2 -> fp32
    hipLaunchKernelGGL(k_gemm_mfma, dim3((M / 128) * 4), dim3(256), 0, stream,
                       hh, hl, hh, hl, 1 << 30, H2,
                       Bt2h, Bt2l, 512, (const float*)nullptr, 0,
                       (u16*)nullptr, (u16*)nullptr, mhB);
    hipLaunchKernelGGL(k_conv2agg, dim3(tc * 128), dim3(256), 0, stream,
                       mhB, rp, csr, dinv, b2l, part);
    hipLaunchKernelGGL(k_pool, dim3(tc), dim3(256), 0, stream, part, t0, tc, zB, znB);
  }

  hipLaunchKernelGGL(k_gru, dim3(T_SEQ), dim3(256), 0, stream, zB, Wih, bih, bhh, cB, cnB, out);
  hipLaunchKernelGGL(k_cpc, dim3(36), dim3(256), 0, stream, zB, cB, znB, cnB, out);
  (void)in_sizes; (void)n_in; (void)out_size;
}

// Round 4
// 3011.138 us; speedup vs baseline: 1.7946x; 1.7946x over previous
//
#include <hip/hip_runtime.h>

#define T_SEQ 64
#define NV 4096
#define NE 65536
#define CIN 128
#define H2 512
#define HO 256
#define NEG_FLT (-3.402823466e38f)

typedef unsigned short u16;
typedef __bf16 bf16x8 __attribute__((ext_vector_type(8)));
typedef float f32x4 __attribute__((ext_vector_type(4)));

__device__ __forceinline__ u16 f2bf(float f){
  unsigned u = __float_as_uint(f);
  unsigned r = (u + 0x7FFFu + ((u >> 16) & 1u)) >> 16;
  return (u16)r;
}
__device__ __forceinline__ float bf2f(u16 h){
  return __uint_as_float(((unsigned)h) << 16);
}

// CK-style async global->LDS, 16B per lane. LDS dest = uniform base + lane*16.
__device__ __forceinline__ void gll16(const u16* g, const uint4* l){
  __builtin_amdgcn_global_load_lds(
      reinterpret_cast<const __attribute__((address_space(1))) unsigned int*>(
          reinterpret_cast<uintptr_t>(g)),
      reinterpret_cast<__attribute__((address_space(3))) unsigned int*>(
          reinterpret_cast<uintptr_t>(l)),
      16, 0, 0);
}

// ---------------- workspace layout ----------------
struct Lay {
  size_t z, c, zn, cn, Bt1h, Bt1l, Bt2h, Bt2l, cnt, fill, rowptr, deginv, csr,
         aggh, aggl, xh, xl, hh, hl, mh, partial, total;
};
static Lay mk_layout(int tc){
  Lay L; size_t o = 0;
  auto tk = [&](size_t b){ size_t p = o; o += ((b + 255) & ~(size_t)255); return p; };
  L.z       = tk((size_t)T_SEQ * HO * 4);
  L.c       = tk((size_t)T_SEQ * HO * 4);
  L.zn      = tk((size_t)T_SEQ * 4);
  L.cn      = tk((size_t)T_SEQ * 4);
  L.Bt1h    = tk((size_t)512 * 256 * 2);
  L.Bt1l    = tk((size_t)512 * 256 * 2);
  L.Bt2h    = tk((size_t)512 * 512 * 2);
  L.Bt2l    = tk((size_t)512 * 512 * 2);
  L.cnt     = tk((size_t)tc * NV * 4);
  L.fill    = tk((size_t)tc * NV * 4);
  L.rowptr  = tk((size_t)tc * (NV + 1) * 4);
  L.deginv  = tk((size_t)tc * NV * 4);
  L.csr     = tk((size_t)tc * NE * 4);
  L.aggh    = tk((size_t)tc * NV * CIN * 2);
  L.aggl    = tk((size_t)tc * NV * CIN * 2);
  L.xh      = tk((size_t)tc * NV * CIN * 2);
  L.xl      = tk((size_t)tc * NV * CIN * 2);
  L.hh      = tk((size_t)tc * NV * H2 * 2);
  L.hl      = tk((size_t)tc * NV * H2 * 2);
  L.mh      = tk((size_t)tc * NV * H2 * 4);
  L.partial = tk((size_t)tc * 128 * HO * 4);
  L.total = o; return L;
}

// ---------------- small kernels ----------------
__global__ void k_init_out(float* out){
  int i = threadIdx.x;
  if (i < 2) out[i] = 0.0f;
}

// B transposed + bf16-split: Bt1[n][k] (512x256), Bt2[n][k] (512x512)
__global__ void k_prep_Bt(const float* __restrict__ W1l, const float* __restrict__ W1r,
                          const float* __restrict__ W2l, const float* __restrict__ W2r,
                          u16* __restrict__ Bt1h, u16* __restrict__ Bt1l,
                          u16* __restrict__ Bt2h, u16* __restrict__ Bt2l){
  int i = blockIdx.x * 256 + threadIdx.x;
  if (i < 512 * 256){
    int n = i >> 8, k = i & 255;
    float v = (k < 128) ? W1l[k * 512 + n] : W1r[(k - 128) * 512 + n];
    u16 h = f2bf(v);
    Bt1h[i] = h; Bt1l[i] = f2bf(v - bf2f(h));
  } else {
    int j = i - 512 * 256;
    if (j < 512 * 512){
      int n = j >> 9, k = j & 511;
      float v = (n < 256) ? W2l[k * 256 + n] : W2r[k * 256 + (n - 256)];
      u16 h = f2bf(v);
      Bt2h[j] = h; Bt2l[j] = f2bf(v - bf2f(h));
    }
  }
}

__global__ void k_zero(int* p, int n){
  int i = blockIdx.x * 256 + threadIdx.x;
  if (i < n) p[i] = 0;
}

__global__ void k_count(const int* __restrict__ ei, int t0, int tc, int* __restrict__ cnt){
  int i = blockIdx.x * 256 + threadIdx.x;
  if (i >= tc * NE) return;
  int tl = i >> 16, e = i & (NE - 1);
  int dst = ei[(size_t)(t0 + tl) * 2 * NE + NE + e];
  atomicAdd(&cnt[tl * NV + dst], 1);
}

__global__ void k_scan(const int* __restrict__ cnt, int* __restrict__ rowptr,
                       float* __restrict__ deginv){
  int tl = blockIdx.x, tid = threadIdx.x;
  __shared__ int s[256];
  int vals[16]; int sum = 0;
  const int* cb = cnt + tl * NV + tid * 16;
  #pragma unroll
  for (int i = 0; i < 16; i++){ vals[i] = cb[i]; sum += vals[i]; }
  s[tid] = sum; __syncthreads();
  for (int off = 1; off < 256; off <<= 1){
    int v = (tid >= off) ? s[tid - off] : 0;
    __syncthreads();
    s[tid] += v;
    __syncthreads();
  }
  int ex = s[tid] - sum;
  int* rp = rowptr + tl * (NV + 1) + tid * 16;
  float* dv = deginv + tl * NV + tid * 16;
  #pragma unroll
  for (int i = 0; i < 16; i++){
    rp[i] = ex; ex += vals[i];
    int d = vals[i] < 1 ? 1 : vals[i];
    dv[i] = 1.0f / (float)d;
  }
  if (tid == 255) rowptr[tl * (NV + 1) + NV] = ex;
}

__global__ void k_fill(const int* __restrict__ ei, int t0, int tc,
                       const int* __restrict__ rowptr, int* __restrict__ fill,
                       int* __restrict__ csr){
  int i = blockIdx.x * 256 + threadIdx.x;
  if (i >= tc * NE) return;
  int tl = i >> 16, e = i & (NE - 1);
  const int* eit = ei + (size_t)(t0 + tl) * 2 * NE;
  int src = eit[e], dst = eit[NE + e];
  int pos = atomicAdd(&fill[tl * NV + dst], 1);
  csr[tl * NE + rowptr[tl * (NV + 1) + dst] + pos] = src;
}

// x slice -> bf16 hi/lo planes
__global__ void k_xsplit(const float* __restrict__ xs, int n4,
                         u16* __restrict__ xh, u16* __restrict__ xl){
  int i = blockIdx.x * 256 + threadIdx.x;
  if (i >= n4) return;
  float4 v = ((const float4*)xs)[i];
  u16 h0 = f2bf(v.x), h1 = f2bf(v.y), h2 = f2bf(v.z), h3 = f2bf(v.w);
  u16 l0 = f2bf(v.x - bf2f(h0)), l1 = f2bf(v.y - bf2f(h1));
  u16 l2 = f2bf(v.z - bf2f(h2)), l3 = f2bf(v.w - bf2f(h3));
  ushort4 hv; hv.x = h0; hv.y = h1; hv.z = h2; hv.w = h3;
  ushort4 lv; lv.x = l0; lv.y = l1; lv.z = l2; lv.w = l3;
  *(ushort4*)(xh + (size_t)i * 4) = hv;
  *(ushort4*)(xl + (size_t)i * 4) = lv;
}

// conv1 aggregation: one wave per (t, v); lanes cover 128 ch as float2; writes bf16 hi/lo
__global__ __launch_bounds__(256) void k_agg1(const float* __restrict__ x, int t0, int tc,
                       const int* __restrict__ rowptr, const int* __restrict__ csr,
                       const float* __restrict__ deginv,
                       u16* __restrict__ aggh, u16* __restrict__ aggl){
  int w = (blockIdx.x * 256 + threadIdx.x) >> 6;
  int lane = threadIdx.x & 63;
  if (w >= tc * NV) return;
  int tl = w >> 12, v = w & (NV - 1);
  const float2* xt = (const float2*)(x + (size_t)(t0 + tl) * NV * CIN);
  int beg = rowptr[tl * (NV + 1) + v], end = rowptr[tl * (NV + 1) + v + 1];
  const int* cs = csr + tl * NE;
  float ax = 0.f, ay = 0.f;
  for (int j = beg; j < end; j++){
    int s = cs[j];
    float2 xv = xt[(size_t)s * 64 + lane];
    ax += xv.x; ay += xv.y;
  }
  float di = deginv[tl * NV + v];
  float vx = ax * di, vy = ay * di;
  u16 hx = f2bf(vx), hy = f2bf(vy);
  u16 lx = f2bf(vx - bf2f(hx)), ly = f2bf(vy - bf2f(hy));
  ushort2 hv; hv.x = hx; hv.y = hy;
  ushort2 lv; lv.x = lx; lv.y = ly;
  ((ushort2*)aggh)[(size_t)w * 64 + lane] = hv;
  ((ushort2*)aggl)[(size_t)w * 64 + lane] = lv;
}

// ---------------- split-bf16 MFMA GEMM (global_load_lds staging) ----------------
// C[M x 512] = A @ B; A = [A0 | A1] split at ksplit (bf16 hi/lo planes, [M][lda]);
// B transposed: Bt[512][K] hi/lo. 3-term: Ah*Bh + Ah*Bl + Al*Bh.
// 128x128 block, 4 waves (2x2 of 64x64), BK=32, fragment-linear LDS filled by
// global_load_lds (no VGPR staging, no ds_write), double-buffered, 1 barrier/step.
__global__ __launch_bounds__(256, 2) void k_gemm_mfma(
    const u16* __restrict__ Ah0, const u16* __restrict__ Al0,
    const u16* __restrict__ Ah1, const u16* __restrict__ Al1,
    int ksplit, int lda,
    const u16* __restrict__ Bh, const u16* __restrict__ Bl, int K,
    const float* __restrict__ bias, int mode,
    u16* __restrict__ OutH, u16* __restrict__ OutL, float* __restrict__ OutF)
{
  // 64 KB: per buffer (2048 uint4): Ah[0,512) Al[512,1024) Bh[1024,1536) Bl[1536,2048)
  __shared__ uint4 lds[4096];
  int tid = threadIdx.x;
  int bm = blockIdx.x >> 2, bn = blockIdx.x & 3;  // bn fastest: A-panel L2 reuse
  size_t row0 = (size_t)bm * 128;
  int col0 = bn * 128;
  int lane = tid & 63, wid = tid >> 6;
  int wm = wid >> 1, wn = wid & 1;
  int l15 = lane & 15, l4 = lane >> 4;

  // wave `wid` stages chunks {2*wid, 2*wid+1} (16 rows/cols each) of all 4 planes.
  // LDS slot for chunk c, lane l: c*64 + l  -> holds row (c*16 + l&15), k-group l>>4.
  size_t aoff[2], boff[2];
  int cslot[2];
  #pragma unroll
  for (int q = 0; q < 2; q++){
    int c = 2 * wid + q;
    aoff[q] = (row0 + c * 16 + l15) * (size_t)lda + (size_t)(l4 * 8);
    boff[q] = (size_t)(col0 + c * 16 + l15) * K + (size_t)(l4 * 8);
    cslot[q] = c * 64;
  }

#define STAGE(T) do { \
    int kk0_ = (T) << 5; \
    const u16* pAh_ = Ah0; const u16* pAl_ = Al0; int kA_ = kk0_; \
    if (kk0_ >= ksplit){ pAh_ = Ah1; pAl_ = Al1; kA_ = kk0_ - ksplit; } \
    int bb_ = ((T) & 1) << 11; \
    _Pragma("unroll") \
    for (int q = 0; q < 2; q++){ \
      gll16(pAh_ + aoff[q] + kA_, &lds[bb_ + cslot[q]]); \
      gll16(pAl_ + aoff[q] + kA_, &lds[bb_ + 512 + cslot[q]]); \
      gll16(Bh + boff[q] + kk0_, &lds[bb_ + 1024 + cslot[q]]); \
      gll16(Bl + boff[q] + kk0_, &lds[bb_ + 1536 + cslot[q]]); \
    } \
  } while (0)

  f32x4 zv = {0.f, 0.f, 0.f, 0.f};
  f32x4 acc[4][4];
  #pragma unroll
  for (int i = 0; i < 4; i++)
    #pragma unroll
    for (int j = 0; j < 4; j++) acc[i][j] = zv;

  STAGE(0);
  __syncthreads();   // vmcnt(0): buf0 ready

  int nt = K >> 5;
  for (int t = 0; t < nt; t++){
    if (t + 1 < nt) STAGE(t + 1);     // issue next-tile loads first (T3 minimum)
    int base = (t & 1) << 11;
    int abase = base + wm * 256;
    int bbase = base + 1024 + wn * 256;
    bf16x8 ah[4], al[4], bh[4], bl[4];
    #pragma unroll
    for (int f = 0; f < 4; f++){
      ah[f] = __builtin_bit_cast(bf16x8, lds[abase + f * 64 + lane]);
      al[f] = __builtin_bit_cast(bf16x8, lds[abase + 512 + f * 64 + lane]);
      bh[f] = __builtin_bit_cast(bf16x8, lds[bbase + f * 64 + lane]);
      bl[f] = __builtin_bit_cast(bf16x8, lds[bbase + 512 + f * 64 + lane]);
    }
    #pragma unroll
    for (int i = 0; i < 4; i++)
      #pragma unroll
      for (int j = 0; j < 4; j++){
        acc[i][j] = __builtin_amdgcn_mfma_f32_16x16x32_bf16(ah[i], bh[j], acc[i][j], 0, 0, 0);
        acc[i][j] = __builtin_amdgcn_mfma_f32_16x16x32_bf16(ah[i], bl[j], acc[i][j], 0, 0, 0);
        acc[i][j] = __builtin_amdgcn_mfma_f32_16x16x32_bf16(al[i], bh[j], acc[i][j], 0, 0, 0);
      }
    __syncthreads();  // drains vmcnt (next buf staged) + lgkmcnt (reads of cur done)
  }
#undef STAGE

  // epilogue: C/D frag layout col=lane&15, row=(lane>>4)*4+reg
  #pragma unroll
  for (int i = 0; i < 4; i++){
    #pragma unroll
    for (int j = 0; j < 4; j++){
      int col = col0 + wn * 64 + j * 16 + l15;
      float bv = bias ? bias[col] : 0.f;
      #pragma unroll
      for (int r = 0; r < 4; r++){
        size_t row = row0 + wm * 64 + i * 16 + l4 * 4 + r;
        float v = acc[i][j][r] + bv;
        if (mode == 1){
          v = fmaxf(v, 0.f);
          u16 h = f2bf(v);
          u16 l = f2bf(v - bf2f(h));
          OutH[row * 512 + col] = h;
          OutL[row * 512 + col] = l;
        } else {
          OutF[row * 512 + col] = v;
        }
      }
    }
  }
}

// conv2 aggregation + finalize + per-block partial max-pool (mh fp32 [M][512]).
__global__ __launch_bounds__(256) void k_conv2agg(
    const float* __restrict__ mh, const int* __restrict__ rowptr,
    const int* __restrict__ csr, const float* __restrict__ deginv,
    const float* __restrict__ b2l, float* __restrict__ partial){
  int blk = blockIdx.x;
  int tl = blk >> 7, nb = blk & 127;
  int wid = threadIdx.x >> 6, lane = threadIdx.x & 63;
  const float4* m4 = (const float4*)mh;
  const int* rp = rowptr + tl * (NV + 1);
  const int* cs = csr + tl * NE;
  float4 bb = ((const float4*)b2l)[lane];
  float4 vmax; vmax.x = NEG_FLT; vmax.y = NEG_FLT; vmax.z = NEG_FLT; vmax.w = NEG_FLT;
  int v0 = nb * 32 + wid * 8;
  for (int q = 0; q < 8; q++){
    int v = v0 + q;
    int beg = rp[v], end = rp[v + 1];
    float4 acc; acc.x = 0.f; acc.y = 0.f; acc.z = 0.f; acc.w = 0.f;
    for (int j = beg; j < end; j++){
      int s = cs[j];
      float4 mv = m4[(size_t)(tl * NV + s) * 128 + lane];
      acc.x += mv.x; acc.y += mv.y; acc.z += mv.z; acc.w += mv.w;
    }
    float di = deginv[tl * NV + v];
    float4 hr = m4[(size_t)(tl * NV + v) * 128 + 64 + lane];
    float4 val;
    val.x = acc.x * di + bb.x + hr.x;
    val.y = acc.y * di + bb.y + hr.y;
    val.z = acc.z * di + bb.z + hr.z;
    val.w = acc.w * di + bb.w + hr.w;
    vmax.x = fmaxf(vmax.x, val.x); vmax.y = fmaxf(vmax.y, val.y);
    vmax.z = fmaxf(vmax.z, val.z); vmax.w = fmaxf(vmax.w, val.w);
  }
  __shared__ float4 sm[4][64];
  sm[wid][lane] = vmax;
  __syncthreads();
  if (wid == 0){
    float4 a = sm[0][lane], b = sm[1][lane], c = sm[2][lane], d = sm[3][lane];
    float4 r;
    r.x = fmaxf(fmaxf(a.x, b.x), fmaxf(c.x, d.x));
    r.y = fmaxf(fmaxf(a.y, b.y), fmaxf(c.y, d.y));
    r.z = fmaxf(fmaxf(a.z, b.z), fmaxf(c.z, d.z));
    r.w = fmaxf(fmaxf(a.w, b.w), fmaxf(c.w, d.w));
    ((float4*)partial)[((size_t)(tl * 128 + nb)) * 64 + lane] = r;
  }
}

__global__ void k_pool(const float* __restrict__ partial, int t0, int tc,
                       float* __restrict__ z, float* __restrict__ zn){
  int tl = blockIdx.x, c = threadIdx.x;
  float m = NEG_FLT;
  for (int b = 0; b < 128; b++)
    m = fmaxf(m, partial[((size_t)(tl * 128 + b)) * HO + c]);
  z[(t0 + tl) * HO + c] = m;
  __shared__ float s[256];
  s[c] = m * m; __syncthreads();
  for (int off = 128; off > 0; off >>= 1){
    if (c < off) s[c] += s[c + off];
    __syncthreads();
  }
  if (c == 0) zn[t0 + tl] = sqrtf(s[0]);
}

__global__ void k_gru(const float* __restrict__ z, const float* __restrict__ Wih,
                      const float* __restrict__ bih, const float* __restrict__ bhh,
                      float* __restrict__ c, float* __restrict__ cn, float* __restrict__ out){
  int s0 = blockIdx.x, j = threadIdx.x;
  __shared__ float zs[256];
  __shared__ float ss[256];
  zs[j] = z[s0 * HO + j];
  __syncthreads();
  const float* wr = Wih + (size_t)j * HO;
  const float* wu = Wih + (size_t)(HO + j) * HO;
  const float* wn = Wih + (size_t)(2 * HO + j) * HO;
  float gr = bih[j], gu = bih[HO + j], gn = bih[2 * HO + j];
  for (int k = 0; k < HO; k++){
    float zv = zs[k];
    gr = fmaf(zv, wr[k], gr);
    gu = fmaf(zv, wu[k], gu);
    gn = fmaf(zv, wn[k], gn);
  }
  float r = 1.f / (1.f + expf(-(gr + bhh[j])));
  float u = 1.f / (1.f + expf(-(gu + bhh[HO + j])));
  float n = tanhf(gn + r * bhh[2 * HO + j]);
  float cv = (1.f - u) * n;
  c[s0 * HO + j] = cv;
  if (s0 < 44) out[2 + s0 * HO + j] = cv;
  ss[j] = cv * cv; __syncthreads();
  for (int off = 128; off > 0; off >>= 1){
    if (j < off) ss[j] += ss[j + off];
    __syncthreads();
  }
  if (j == 0) cn[s0] = sqrtf(ss[0]);
}

__global__ void k_cpc(const float* __restrict__ z, const float* __restrict__ c,
                      const float* __restrict__ zn, const float* __restrict__ cn,
                      float* __restrict__ out){
  int tt = blockIdx.x;
  int ts = 8 + tt;
  int tid = threadIdx.x;
  __shared__ float ct[256];
  __shared__ float tot[32];
  ct[tid] = c[ts * HO + tid];
  __syncthreads();
  int g = tid >> 3, r = tid & 7;
  int i = g >> 3, j = g & 7;
  int idx = ts + ((j == 0) ? (i + 1) : (i + j + 10));
  const float* zr = z + idx * HO;
  float s = 0.f;
  for (int k = r; k < HO; k += 8) s = fmaf(zr[k], ct[k], s);
  s += __shfl_down(s, 4, 8);
  s += __shfl_down(s, 2, 8);
  s += __shfl_down(s, 1, 8);
  if (r == 0){
    float den = fmaxf(zn[idx], 1e-8f) * fmaxf(cn[ts], 1e-8f);
    tot[g] = s / den;
  }
  __syncthreads();
  if (tid < 4){
    const float* tr = tot + tid * 8;
    float m = tr[0];
    for (int q = 1; q < 8; q++) m = fmaxf(m, tr[q]);
    float se = 0.f;
    for (int q = 0; q < 8; q++) se += expf(tr[q] - m);
    float lse = m + logf(se);
    float nce = (lse - tr[0]) * (1.0f / 144.0f);
    float corr = (tr[0] == m) ? (1.0f / 144.0f) : 0.f;
    atomicAdd(&out[0], nce);
    atomicAdd(&out[1], corr);
  }
}

// ---------------- launch ----------------
extern "C" void kernel_launch(void* const* d_in, const int* in_sizes, int n_in,
                              void* d_out, int out_size, void* d_ws, size_t ws_size,
                              hipStream_t stream){
  const float* x   = (const float*)d_in[0];
  const int*   ei  = (const int*)  d_in[1];
  const float* W1l = (const float*)d_in[2];
  const float* b1l = (const float*)d_in[3];
  const float* W1r = (const float*)d_in[4];
  const float* W2l = (const float*)d_in[5];
  const float* b2l = (const float*)d_in[6];
  const float* W2r = (const float*)d_in[7];
  const float* Wih = (const float*)d_in[8];
  const float* bih = (const float*)d_in[10];
  const float* bhh = (const float*)d_in[11];
  float* out = (float*)d_out;

  int tc = 64;
  while (tc > 1 && mk_layout(tc).total > ws_size) tc >>= 1;
  Lay L = mk_layout(tc);
  char* w = (char*)d_ws;
  float* zB   = (float*)(w + L.z);
  float* cB   = (float*)(w + L.c);
  float* znB  = (float*)(w + L.zn);
  float* cnB  = (float*)(w + L.cn);
  u16*   Bt1h = (u16*)  (w + L.Bt1h);
  u16*   Bt1l = (u16*)  (w + L.Bt1l);
  u16*   Bt2h = (u16*)  (w + L.Bt2h);
  u16*   Bt2l = (u16*)  (w + L.Bt2l);
  int*   cnt  = (int*)  (w + L.cnt);
  int*   fill = (int*)  (w + L.fill);
  int*   rp   = (int*)  (w + L.rowptr);
  float* dinv = (float*)(w + L.deginv);
  int*   csr  = (int*)  (w + L.csr);
  u16*   aggh = (u16*)  (w + L.aggh);
  u16*   aggl = (u16*)  (w + L.aggl);
  u16*   xh   = (u16*)  (w + L.xh);
  u16*   xl   = (u16*)  (w + L.xl);
  u16*   hh   = (u16*)  (w + L.hh);
  u16*   hl   = (u16*)  (w + L.hl);
  float* mhB  = (float*)(w + L.mh);
  float* part = (float*)(w + L.partial);

  hipLaunchKernelGGL(k_init_out, dim3(1), dim3(64), 0, stream, out);
  hipLaunchKernelGGL(k_prep_Bt, dim3(1536), dim3(256), 0, stream,
                     W1l, W1r, W2l, W2r, Bt1h, Bt1l, Bt2h, Bt2l);

  for (int t0 = 0; t0 < T_SEQ; t0 += tc){
    int nE = tc * NE;
    int M = tc * NV;
    hipLaunchKernelGGL(k_zero, dim3((tc * NV + 255) / 256), dim3(256), 0, stream, cnt, tc * NV);
    hipLaunchKernelGGL(k_zero, dim3((tc * NV + 255) / 256), dim3(256), 0, stream, fill, tc * NV);
    hipLaunchKernelGGL(k_count, dim3((nE + 255) / 256), dim3(256), 0, stream, ei, t0, tc, cnt);
    hipLaunchKernelGGL(k_scan, dim3(tc), dim3(256), 0, stream, cnt, rp, dinv);
    hipLaunchKernelGGL(k_fill, dim3((nE + 255) / 256), dim3(256), 0, stream, ei, t0, tc, rp, fill, csr);
    hipLaunchKernelGGL(k_agg1, dim3(tc * NV / 4), dim3(256), 0, stream,
                       x, t0, tc, rp, csr, dinv, aggh, aggl);
    int n4 = tc * NV * CIN / 4;
    hipLaunchKernelGGL(k_xsplit, dim3((n4 + 255) / 256), dim3(256), 0, stream,
                       x + (size_t)t0 * NV * CIN, n4, xh, xl);
    // conv1: h = relu([agg | x] @ B1 + b1l) -> bf16 hi/lo planes
    hipLaunchKernelGGL(k_gemm_mfma, dim3((M / 128) * 4), dim3(256), 0, stream,
                       aggh, aggl, xh, xl, 128, CIN,
                       Bt1h, Bt1l, 256, b1l, 1, hh, hl, (float*)nullptr);
    // conv2: mh = h @ B2 -> fp32
    hipLaunchKernelGGL(k_gemm_mfma, dim3((M / 128) * 4), dim3(256), 0, stream,
                       hh, hl, hh, hl, 1 << 30, H2,
                       Bt2h, Bt2l, 512, (const float*)nullptr, 0,
                       (u16*)nullptr, (u16*)nullptr, mhB);
    hipLaunchKernelGGL(k_conv2agg, dim3(tc * 128), dim3(256), 0, stream,
                       mhB, rp, csr, dinv, b2l, part);
    hipLaunchKernelGGL(k_pool, dim3(tc), dim3(256), 0, stream, part, t0, tc, zB, znB);
  }

  hipLaunchKernelGGL(k_gru, dim3(T_SEQ), dim3(256), 0, stream, zB, Wih, bih, bhh, cB, cnB, out);
  hipLaunchKernelGGL(k_cpc, dim3(36), dim3(256), 0, stream, zB, cB, znB, cnB, out);
  (void)in_sizes; (void)n_in; (void)out_size;
}

// Round 5
// 2433.398 us; speedup vs baseline: 2.2206x; 1.2374x over previous
//
#include <hip/hip_runtime.h>

#define T_SEQ 64
#define NV 4096
#define NE 65536
#define CIN 128
#define H2 512
#define HO 256
#define NEG_FLT (-3.402823466e38f)

typedef unsigned short u16;
typedef __bf16 bf16x8 __attribute__((ext_vector_type(8)));
typedef float f32x4 __attribute__((ext_vector_type(4)));

__device__ __forceinline__ u16 f2bf(float f){
  unsigned u = __float_as_uint(f);
  unsigned r = (u + 0x7FFFu + ((u >> 16) & 1u)) >> 16;
  return (u16)r;
}
__device__ __forceinline__ float bf2f(u16 h){
  return __uint_as_float(((unsigned)h) << 16);
}

// XCD-aware block swizzle (T1): grid must be a multiple of 8. Blocks are
// dispatched round-robin across the 8 XCDs; this remap gives each XCD a
// CONTIGUOUS chunk of the work space so per-t gather footprints stay L2-resident.
__device__ __forceinline__ int swz8(){
  return (int)((blockIdx.x & 7) * (gridDim.x >> 3) + (blockIdx.x >> 3));
}

// CK-style async global->LDS, 16B per lane. LDS dest = uniform base + lane*16.
__device__ __forceinline__ void gll16(const u16* g, const uint4* l){
  __builtin_amdgcn_global_load_lds(
      reinterpret_cast<const __attribute__((address_space(1))) unsigned int*>(
          reinterpret_cast<uintptr_t>(g)),
      reinterpret_cast<__attribute__((address_space(3))) unsigned int*>(
          reinterpret_cast<uintptr_t>(l)),
      16, 0, 0);
}

// ---------------- workspace layout ----------------
struct Lay {
  size_t z, c, zn, cn, Bt1h, Bt1l, Bt2h, Bt2l, cnt, fill, rowptr, deginv, csr,
         aggh, aggl, xh, xl, hh, hl, mh, partial, total;
};
static Lay mk_layout(int tc){
  Lay L; size_t o = 0;
  auto tk = [&](size_t b){ size_t p = o; o += ((b + 255) & ~(size_t)255); return p; };
  L.z       = tk((size_t)T_SEQ * HO * 4);
  L.c       = tk((size_t)T_SEQ * HO * 4);
  L.zn      = tk((size_t)T_SEQ * 4);
  L.cn      = tk((size_t)T_SEQ * 4);
  L.Bt1h    = tk((size_t)512 * 256 * 2);
  L.Bt1l    = tk((size_t)512 * 256 * 2);
  L.Bt2h    = tk((size_t)512 * 512 * 2);
  L.Bt2l    = tk((size_t)512 * 512 * 2);
  L.cnt     = tk((size_t)tc * NV * 4);
  L.fill    = tk((size_t)tc * NV * 4);
  L.rowptr  = tk((size_t)tc * (NV + 1) * 4);
  L.deginv  = tk((size_t)tc * NV * 4);
  L.csr     = tk((size_t)tc * NE * 4);
  L.aggh    = tk((size_t)tc * NV * CIN * 2);
  L.aggl    = tk((size_t)tc * NV * CIN * 2);
  L.xh      = tk((size_t)tc * NV * CIN * 2);
  L.xl      = tk((size_t)tc * NV * CIN * 2);
  L.hh      = tk((size_t)tc * NV * H2 * 2);
  L.hl      = tk((size_t)tc * NV * H2 * 2);
  L.mh      = tk((size_t)tc * NV * H2 * 4);
  L.partial = tk((size_t)tc * 128 * HO * 4);
  L.total = o; return L;
}

// ---------------- small kernels ----------------
__global__ void k_init_out(float* out){
  int i = threadIdx.x;
  if (i < 2) out[i] = 0.0f;
}

// B transposed + bf16-split: Bt1[n][k] (512x256), Bt2[n][k] (512x512)
__global__ void k_prep_Bt(const float* __restrict__ W1l, const float* __restrict__ W1r,
                          const float* __restrict__ W2l, const float* __restrict__ W2r,
                          u16* __restrict__ Bt1h, u16* __restrict__ Bt1l,
                          u16* __restrict__ Bt2h, u16* __restrict__ Bt2l){
  int i = blockIdx.x * 256 + threadIdx.x;
  if (i < 512 * 256){
    int n = i >> 8, k = i & 255;
    float v = (k < 128) ? W1l[k * 512 + n] : W1r[(k - 128) * 512 + n];
    u16 h = f2bf(v);
    Bt1h[i] = h; Bt1l[i] = f2bf(v - bf2f(h));
  } else {
    int j = i - 512 * 256;
    if (j < 512 * 512){
      int n = j >> 9, k = j & 511;
      float v = (n < 256) ? W2l[k * 256 + n] : W2r[k * 256 + (n - 256)];
      u16 h = f2bf(v);
      Bt2h[j] = h; Bt2l[j] = f2bf(v - bf2f(h));
    }
  }
}

__global__ void k_zero(int* p, int n){
  int i = blockIdx.x * 256 + threadIdx.x;
  if (i < n) p[i] = 0;
}

__global__ void k_count(const int* __restrict__ ei, int t0, int tc, int* __restrict__ cnt){
  int i = blockIdx.x * 256 + threadIdx.x;
  if (i >= tc * NE) return;
  int tl = i >> 16, e = i & (NE - 1);
  int dst = ei[(size_t)(t0 + tl) * 2 * NE + NE + e];
  atomicAdd(&cnt[tl * NV + dst], 1);
}

__global__ void k_scan(const int* __restrict__ cnt, int* __restrict__ rowptr,
                       float* __restrict__ deginv){
  int tl = blockIdx.x, tid = threadIdx.x;
  __shared__ int s[256];
  int vals[16]; int sum = 0;
  const int* cb = cnt + tl * NV + tid * 16;
  #pragma unroll
  for (int i = 0; i < 16; i++){ vals[i] = cb[i]; sum += vals[i]; }
  s[tid] = sum; __syncthreads();
  for (int off = 1; off < 256; off <<= 1){
    int v = (tid >= off) ? s[tid - off] : 0;
    __syncthreads();
    s[tid] += v;
    __syncthreads();
  }
  int ex = s[tid] - sum;
  int* rp = rowptr + tl * (NV + 1) + tid * 16;
  float* dv = deginv + tl * NV + tid * 16;
  #pragma unroll
  for (int i = 0; i < 16; i++){
    rp[i] = ex; ex += vals[i];
    int d = vals[i] < 1 ? 1 : vals[i];
    dv[i] = 1.0f / (float)d;
  }
  if (tid == 255) rowptr[tl * (NV + 1) + NV] = ex;
}

__global__ void k_fill(const int* __restrict__ ei, int t0, int tc,
                       const int* __restrict__ rowptr, int* __restrict__ fill,
                       int* __restrict__ csr){
  int i = blockIdx.x * 256 + threadIdx.x;
  if (i >= tc * NE) return;
  int tl = i >> 16, e = i & (NE - 1);
  const int* eit = ei + (size_t)(t0 + tl) * 2 * NE;
  int src = eit[e], dst = eit[NE + e];
  int pos = atomicAdd(&fill[tl * NV + dst], 1);
  csr[tl * NE + rowptr[tl * (NV + 1) + dst] + pos] = src;
}

// x slice -> bf16 hi/lo planes
__global__ void k_xsplit(const float* __restrict__ xs, int n4,
                         u16* __restrict__ xh, u16* __restrict__ xl){
  int i = blockIdx.x * 256 + threadIdx.x;
  if (i >= n4) return;
  float4 v = ((const float4*)xs)[i];
  u16 h0 = f2bf(v.x), h1 = f2bf(v.y), h2 = f2bf(v.z), h3 = f2bf(v.w);
  u16 l0 = f2bf(v.x - bf2f(h0)), l1 = f2bf(v.y - bf2f(h1));
  u16 l2 = f2bf(v.z - bf2f(h2)), l3 = f2bf(v.w - bf2f(h3));
  ushort4 hv; hv.x = h0; hv.y = h1; hv.z = h2; hv.w = h3;
  ushort4 lv; lv.x = l0; lv.y = l1; lv.z = l2; lv.w = l3;
  *(ushort4*)(xh + (size_t)i * 4) = hv;
  *(ushort4*)(xl + (size_t)i * 4) = lv;
}

// conv1 aggregation: one wave per (t, v); lanes cover 128 ch as float2; writes bf16 hi/lo.
// XCD-swizzled: per-t x slice (2 MB) stays L2-resident per XCD.
__global__ __launch_bounds__(256) void k_agg1(const float* __restrict__ x, int t0, int tc,
                       const int* __restrict__ rowptr, const int* __restrict__ csr,
                       const float* __restrict__ deginv,
                       u16* __restrict__ aggh, u16* __restrict__ aggl){
  int bid = swz8();
  int w = (bid * 256 + threadIdx.x) >> 6;
  int lane = threadIdx.x & 63;
  if (w >= tc * NV) return;
  int tl = w >> 12, v = w & (NV - 1);
  const float2* xt = (const float2*)(x + (size_t)(t0 + tl) * NV * CIN);
  int beg = rowptr[tl * (NV + 1) + v], end = rowptr[tl * (NV + 1) + v + 1];
  const int* cs = csr + tl * NE;
  float ax = 0.f, ay = 0.f;
  int j = beg;
  for (; j + 1 < end; j += 2){
    int s0 = cs[j], s1 = cs[j + 1];
    float2 x0 = xt[(size_t)s0 * 64 + lane];
    float2 x1 = xt[(size_t)s1 * 64 + lane];
    ax += x0.x + x1.x; ay += x0.y + x1.y;
  }
  if (j < end){
    int s0 = cs[j];
    float2 x0 = xt[(size_t)s0 * 64 + lane];
    ax += x0.x; ay += x0.y;
  }
  float di = deginv[tl * NV + v];
  float vx = ax * di, vy = ay * di;
  u16 hx = f2bf(vx), hy = f2bf(vy);
  u16 lx = f2bf(vx - bf2f(hx)), ly = f2bf(vy - bf2f(hy));
  ushort2 hv; hv.x = hx; hv.y = hy;
  ushort2 lv; lv.x = lx; lv.y = ly;
  ((ushort2*)aggh)[(size_t)w * 64 + lane] = hv;
  ((ushort2*)aggl)[(size_t)w * 64 + lane] = lv;
}

// ---------------- split-bf16 MFMA GEMM (global_load_lds staging) ----------------
// C[M x 512] = A @ B; A = [A0 | A1] split at ksplit (bf16 hi/lo planes, [M][lda]);
// B transposed: Bt[512][K] hi/lo. 3-term: Ah*Bh + Ah*Bl + Al*Bh.
// 128x128 block, 4 waves (2x2 of 64x64), BK=32, fragment-linear LDS filled by
// global_load_lds, double-buffered, 1 barrier/step. XCD-swizzled: the 4 bn-tiles
// sharing an A panel land on the SAME XCD -> A read once from HBM per XCD.
__global__ __launch_bounds__(256, 2) void k_gemm_mfma(
    const u16* __restrict__ Ah0, const u16* __restrict__ Al0,
    const u16* __restrict__ Ah1, const u16* __restrict__ Al1,
    int ksplit, int lda,
    const u16* __restrict__ Bh, const u16* __restrict__ Bl, int K,
    const float* __restrict__ bias, int mode,
    u16* __restrict__ OutH, u16* __restrict__ OutL, float* __restrict__ OutF)
{
  // 64 KB: per buffer (2048 uint4): Ah[0,512) Al[512,1024) Bh[1024,1536) Bl[1536,2048)
  __shared__ uint4 lds[4096];
  int tid = threadIdx.x;
  int bid = swz8();
  int bm = bid >> 2, bn = bid & 3;   // bn fastest within an XCD's contiguous chunk
  size_t row0 = (size_t)bm * 128;
  int col0 = bn * 128;
  int lane = tid & 63, wid = tid >> 6;
  int wm = wid >> 1, wn = wid & 1;
  int l15 = lane & 15, l4 = lane >> 4;

  // wave `wid` stages chunks {2*wid, 2*wid+1} (16 rows/cols each) of all 4 planes.
  // LDS slot for chunk c, lane l: c*64 + l  -> holds row (c*16 + l&15), k-group l>>4.
  size_t aoff[2], boff[2];
  int cslot[2];
  #pragma unroll
  for (int q = 0; q < 2; q++){
    int c = 2 * wid + q;
    aoff[q] = (row0 + c * 16 + l15) * (size_t)lda + (size_t)(l4 * 8);
    boff[q] = (size_t)(col0 + c * 16 + l15) * K + (size_t)(l4 * 8);
    cslot[q] = c * 64;
  }

#define STAGE(T) do { \
    int kk0_ = (T) << 5; \
    const u16* pAh_ = Ah0; const u16* pAl_ = Al0; int kA_ = kk0_; \
    if (kk0_ >= ksplit){ pAh_ = Ah1; pAl_ = Al1; kA_ = kk0_ - ksplit; } \
    int bb_ = ((T) & 1) << 11; \
    _Pragma("unroll") \
    for (int q = 0; q < 2; q++){ \
      gll16(pAh_ + aoff[q] + kA_, &lds[bb_ + cslot[q]]); \
      gll16(pAl_ + aoff[q] + kA_, &lds[bb_ + 512 + cslot[q]]); \
      gll16(Bh + boff[q] + kk0_, &lds[bb_ + 1024 + cslot[q]]); \
      gll16(Bl + boff[q] + kk0_, &lds[bb_ + 1536 + cslot[q]]); \
    } \
  } while (0)

  f32x4 zv = {0.f, 0.f, 0.f, 0.f};
  f32x4 acc[4][4];
  #pragma unroll
  for (int i = 0; i < 4; i++)
    #pragma unroll
    for (int j = 0; j < 4; j++) acc[i][j] = zv;

  STAGE(0);
  __syncthreads();   // vmcnt(0): buf0 ready

  int nt = K >> 5;
  for (int t = 0; t < nt; t++){
    if (t + 1 < nt) STAGE(t + 1);     // issue next-tile loads first
    int base = (t & 1) << 11;
    int abase = base + wm * 256;
    int bbase = base + 1024 + wn * 256;
    bf16x8 ah[4], al[4], bh[4], bl[4];
    #pragma unroll
    for (int f = 0; f < 4; f++){
      ah[f] = __builtin_bit_cast(bf16x8, lds[abase + f * 64 + lane]);
      al[f] = __builtin_bit_cast(bf16x8, lds[abase + 512 + f * 64 + lane]);
      bh[f] = __builtin_bit_cast(bf16x8, lds[bbase + f * 64 + lane]);
      bl[f] = __builtin_bit_cast(bf16x8, lds[bbase + 512 + f * 64 + lane]);
    }
    #pragma unroll
    for (int i = 0; i < 4; i++)
      #pragma unroll
      for (int j = 0; j < 4; j++){
        acc[i][j] = __builtin_amdgcn_mfma_f32_16x16x32_bf16(ah[i], bh[j], acc[i][j], 0, 0, 0);
        acc[i][j] = __builtin_amdgcn_mfma_f32_16x16x32_bf16(ah[i], bl[j], acc[i][j], 0, 0, 0);
        acc[i][j] = __builtin_amdgcn_mfma_f32_16x16x32_bf16(al[i], bh[j], acc[i][j], 0, 0, 0);
      }
    __syncthreads();  // drains vmcnt (next buf staged) + lgkmcnt (reads of cur done)
  }
#undef STAGE

  // epilogue: C/D frag layout col=lane&15, row=(lane>>4)*4+reg
  #pragma unroll
  for (int i = 0; i < 4; i++){
    #pragma unroll
    for (int j = 0; j < 4; j++){
      int col = col0 + wn * 64 + j * 16 + l15;
      float bv = bias ? bias[col] : 0.f;
      #pragma unroll
      for (int r = 0; r < 4; r++){
        size_t row = row0 + wm * 64 + i * 16 + l4 * 4 + r;
        float v = acc[i][j][r] + bv;
        if (mode == 1){
          v = fmaxf(v, 0.f);
          u16 h = f2bf(v);
          u16 l = f2bf(v - bf2f(h));
          OutH[row * 512 + col] = h;
          OutL[row * 512 + col] = l;
        } else {
          OutF[row * 512 + col] = v;
        }
      }
    }
  }
}

// conv2 aggregation + finalize + per-block partial max-pool (mh fp32 [M][512]).
// XCD-swizzled: per-t m slice (4 MB) ~= one XCD L2 -> gather becomes L2 hits.
__global__ __launch_bounds__(256) void k_conv2agg(
    const float* __restrict__ mh, const int* __restrict__ rowptr,
    const int* __restrict__ csr, const float* __restrict__ deginv,
    const float* __restrict__ b2l, float* __restrict__ partial){
  int blk = swz8();
  int tl = blk >> 7, nb = blk & 127;
  int wid = threadIdx.x >> 6, lane = threadIdx.x & 63;
  const float4* m4 = (const float4*)mh;
  const int* rp = rowptr + tl * (NV + 1);
  const int* cs = csr + tl * NE;
  size_t tB = (size_t)tl * NV;
  float4 bb = ((const float4*)b2l)[lane];
  float4 vmax; vmax.x = NEG_FLT; vmax.y = NEG_FLT; vmax.z = NEG_FLT; vmax.w = NEG_FLT;
  int v0 = nb * 32 + wid * 8;
  for (int q = 0; q < 8; q++){
    int v = v0 + q;
    int beg = rp[v], end = rp[v + 1];
    float4 acc; acc.x = 0.f; acc.y = 0.f; acc.z = 0.f; acc.w = 0.f;
    int j = beg;
    for (; j + 1 < end; j += 2){
      int s0 = cs[j], s1 = cs[j + 1];
      float4 a0 = m4[(tB + s0) * 128 + lane];
      float4 a1 = m4[(tB + s1) * 128 + lane];
      acc.x += a0.x + a1.x; acc.y += a0.y + a1.y;
      acc.z += a0.z + a1.z; acc.w += a0.w + a1.w;
    }
    if (j < end){
      int s0 = cs[j];
      float4 a0 = m4[(tB + s0) * 128 + lane];
      acc.x += a0.x; acc.y += a0.y; acc.z += a0.z; acc.w += a0.w;
    }
    float di = deginv[tl * NV + v];
    float4 hr = m4[(tB + v) * 128 + 64 + lane];
    float4 val;
    val.x = acc.x * di + bb.x + hr.x;
    val.y = acc.y * di + bb.y + hr.y;
    val.z = acc.z * di + bb.z + hr.z;
    val.w = acc.w * di + bb.w + hr.w;
    vmax.x = fmaxf(vmax.x, val.x); vmax.y = fmaxf(vmax.y, val.y);
    vmax.z = fmaxf(vmax.z, val.z); vmax.w = fmaxf(vmax.w, val.w);
  }
  __shared__ float4 sm[4][64];
  sm[wid][lane] = vmax;
  __syncthreads();
  if (wid == 0){
    float4 a = sm[0][lane], b = sm[1][lane], c = sm[2][lane], d = sm[3][lane];
    float4 r;
    r.x = fmaxf(fmaxf(a.x, b.x), fmaxf(c.x, d.x));
    r.y = fmaxf(fmaxf(a.y, b.y), fmaxf(c.y, d.y));
    r.z = fmaxf(fmaxf(a.z, b.z), fmaxf(c.z, d.z));
    r.w = fmaxf(fmaxf(a.w, b.w), fmaxf(c.w, d.w));
    ((float4*)partial)[((size_t)(tl * 128 + nb)) * 64 + lane] = r;
  }
}

__global__ void k_pool(const float* __restrict__ partial, int t0, int tc,
                       float* __restrict__ z, float* __restrict__ zn){
  int tl = blockIdx.x, c = threadIdx.x;
  float m = NEG_FLT;
  for (int b = 0; b < 128; b++)
    m = fmaxf(m, partial[((size_t)(tl * 128 + b)) * HO + c]);
  z[(t0 + tl) * HO + c] = m;
  __shared__ float s[256];
  s[c] = m * m; __syncthreads();
  for (int off = 128; off > 0; off >>= 1){
    if (c < off) s[c] += s[c + off];
    __syncthreads();
  }
  if (c == 0) zn[t0 + tl] = sqrtf(s[0]);
}

__global__ void k_gru(const float* __restrict__ z, const float* __restrict__ Wih,
                      const float* __restrict__ bih, const float* __restrict__ bhh,
                      float* __restrict__ c, float* __restrict__ cn, float* __restrict__ out){
  int s0 = blockIdx.x, j = threadIdx.x;
  __shared__ float zs[256];
  __shared__ float ss[256];
  zs[j] = z[s0 * HO + j];
  __syncthreads();
  const float* wr = Wih + (size_t)j * HO;
  const float* wu = Wih + (size_t)(HO + j) * HO;
  const float* wn = Wih + (size_t)(2 * HO + j) * HO;
  float gr = bih[j], gu = bih[HO + j], gn = bih[2 * HO + j];
  for (int k = 0; k < HO; k++){
    float zv = zs[k];
    gr = fmaf(zv, wr[k], gr);
    gu = fmaf(zv, wu[k], gu);
    gn = fmaf(zv, wn[k], gn);
  }
  float r = 1.f / (1.f + expf(-(gr + bhh[j])));
  float u = 1.f / (1.f + expf(-(gu + bhh[HO + j])));
  float n = tanhf(gn + r * bhh[2 * HO + j]);
  float cv = (1.f - u) * n;
  c[s0 * HO + j] = cv;
  if (s0 < 44) out[2 + s0 * HO + j] = cv;
  ss[j] = cv * cv; __syncthreads();
  for (int off = 128; off > 0; off >>= 1){
    if (j < off) ss[j] += ss[j + off];
    __syncthreads();
  }
  if (j == 0) cn[s0] = sqrtf(ss[0]);
}

__global__ void k_cpc(const float* __restrict__ z, const float* __restrict__ c,
                      const float* __restrict__ zn, const float* __restrict__ cn,
                      float* __restrict__ out){
  int tt = blockIdx.x;
  int ts = 8 + tt;
  int tid = threadIdx.x;
  __shared__ float ct[256];
  __shared__ float tot[32];
  ct[tid] = c[ts * HO + tid];
  __syncthreads();
  int g = tid >> 3, r = tid & 7;
  int i = g >> 3, j = g & 7;
  int idx = ts + ((j == 0) ? (i + 1) : (i + j + 10));
  const float* zr = z + idx * HO;
  float s = 0.f;
  for (int k = r; k < HO; k += 8) s = fmaf(zr[k], ct[k], s);
  s += __shfl_down(s, 4, 8);
  s += __shfl_down(s, 2, 8);
  s += __shfl_down(s, 1, 8);
  if (r == 0){
    float den = fmaxf(zn[idx], 1e-8f) * fmaxf(cn[ts], 1e-8f);
    tot[g] = s / den;
  }
  __syncthreads();
  if (tid < 4){
    const float* tr = tot + tid * 8;
    float m = tr[0];
    for (int q = 1; q < 8; q++) m = fmaxf(m, tr[q]);
    float se = 0.f;
    for (int q = 0; q < 8; q++) se += expf(tr[q] - m);
    float lse = m + logf(se);
    float nce = (lse - tr[0]) * (1.0f / 144.0f);
    float corr = (tr[0] == m) ? (1.0f / 144.0f) : 0.f;
    atomicAdd(&out[0], nce);
    atomicAdd(&out[1], corr);
  }
}

// ---------------- launch ----------------
extern "C" void kernel_launch(void* const* d_in, const int* in_sizes, int n_in,
                              void* d_out, int out_size, void* d_ws, size_t ws_size,
                              hipStream_t stream){
  const float* x   = (const float*)d_in[0];
  const int*   ei  = (const int*)  d_in[1];
  const float* W1l = (const float*)d_in[2];
  const float* b1l = (const float*)d_in[3];
  const float* W1r = (const float*)d_in[4];
  const float* W2l = (const float*)d_in[5];
  const float* b2l = (const float*)d_in[6];
  const float* W2r = (const float*)d_in[7];
  const float* Wih = (const float*)d_in[8];
  const float* bih = (const float*)d_in[10];
  const float* bhh = (const float*)d_in[11];
  float* out = (float*)d_out;

  int tc = 64;
  while (tc > 1 && mk_layout(tc).total > ws_size) tc >>= 1;
  Lay L = mk_layout(tc);
  char* w = (char*)d_ws;
  float* zB   = (float*)(w + L.z);
  float* cB   = (float*)(w + L.c);
  float* znB  = (float*)(w + L.zn);
  float* cnB  = (float*)(w + L.cn);
  u16*   Bt1h = (u16*)  (w + L.Bt1h);
  u16*   Bt1l = (u16*)  (w + L.Bt1l);
  u16*   Bt2h = (u16*)  (w + L.Bt2h);
  u16*   Bt2l = (u16*)  (w + L.Bt2l);
  int*   cnt  = (int*)  (w + L.cnt);
  int*   fill = (int*)  (w + L.fill);
  int*   rp   = (int*)  (w + L.rowptr);
  float* dinv = (float*)(w + L.deginv);
  int*   csr  = (int*)  (w + L.csr);
  u16*   aggh = (u16*)  (w + L.aggh);
  u16*   aggl = (u16*)  (w + L.aggl);
  u16*   xh   = (u16*)  (w + L.xh);
  u16*   xl   = (u16*)  (w + L.xl);
  u16*   hh   = (u16*)  (w + L.hh);
  u16*   hl   = (u16*)  (w + L.hl);
  float* mhB  = (float*)(w + L.mh);
  float* part = (float*)(w + L.partial);

  hipLaunchKernelGGL(k_init_out, dim3(1), dim3(64), 0, stream, out);
  hipLaunchKernelGGL(k_prep_Bt, dim3(1536), dim3(256), 0, stream,
                     W1l, W1r, W2l, W2r, Bt1h, Bt1l, Bt2h, Bt2l);

  for (int t0 = 0; t0 < T_SEQ; t0 += tc){
    int nE = tc * NE;
    int M = tc * NV;
    hipLaunchKernelGGL(k_zero, dim3((tc * NV + 255) / 256), dim3(256), 0, stream, cnt, tc * NV);
    hipLaunchKernelGGL(k_zero, dim3((tc * NV + 255) / 256), dim3(256), 0, stream, fill, tc * NV);
    hipLaunchKernelGGL(k_count, dim3((nE + 255) / 256), dim3(256), 0, stream, ei, t0, tc, cnt);
    hipLaunchKernelGGL(k_scan, dim3(tc), dim3(256), 0, stream, cnt, rp, dinv);
    hipLaunchKernelGGL(k_fill, dim3((nE + 255) / 256), dim3(256), 0, stream, ei, t0, tc, rp, fill, csr);
    hipLaunchKernelGGL(k_agg1, dim3(tc * NV / 4), dim3(256), 0, stream,
                       x, t0, tc, rp, csr, dinv, aggh, aggl);
    int n4 = tc * NV * CIN / 4;
    hipLaunchKernelGGL(k_xsplit, dim3((n4 + 255) / 256), dim3(256), 0, stream,
                       x + (size_t)t0 * NV * CIN, n4, xh, xl);
    // conv1: h = relu([agg | x] @ B1 + b1l) -> bf16 hi/lo planes
    hipLaunchKernelGGL(k_gemm_mfma, dim3((M / 128) * 4), dim3(256), 0, stream,
                       aggh, aggl, xh, xl, 128, CIN,
                       Bt1h, Bt1l, 256, b1l, 1, hh, hl, (float*)nullptr);
    // conv2: mh = h @ B2 -> fp32
    hipLaunchKernelGGL(k_gemm_mfma, dim3((M / 128) * 4), dim3(256), 0, stream,
                       hh, hl, hh, hl, 1 << 30, H2,
                       Bt2h, Bt2l, 512, (const float*)nullptr, 0,
                       (u16*)nullptr, (u16*)nullptr, mhB);
    hipLaunchKernelGGL(k_conv2agg, dim3(tc * 128), dim3(256), 0, stream,
                       mhB, rp, csr, dinv, b2l, part);
    hipLaunchKernelGGL(k_pool, dim3(tc), dim3(256), 0, stream, part, t0, tc, zB, znB);
  }

  hipLaunchKernelGGL(k_gru, dim3(T_SEQ), dim3(256), 0, stream, zB, Wih, bih, bhh, cB, cnB, out);
  hipLaunchKernelGGL(k_cpc, dim3(36), dim3(256), 0, stream, zB, cB, znB, cnB, out);
  (void)in_sizes; (void)n_in; (void)out_size;
}

// Round 6
// 2301.061 us; speedup vs baseline: 2.3484x; 1.0575x over previous
//
#include <hip/hip_runtime.h>

#define T_SEQ 64
#define NV 4096
#define NE 65536
#define CIN 128
#define H2 512
#define HO 256
#define NEG_FLT (-3.402823466e38f)

typedef unsigned short u16;
typedef __bf16 bf16x8 __attribute__((ext_vector_type(8)));
typedef float f32x4 __attribute__((ext_vector_type(4)));

__device__ __forceinline__ u16 f2bf(float f){
  unsigned u = __float_as_uint(f);
  unsigned r = (u + 0x7FFFu + ((u >> 16) & 1u)) >> 16;
  return (u16)r;
}
__device__ __forceinline__ float bf2f(u16 h){
  return __uint_as_float(((unsigned)h) << 16);
}

// XCD-aware block swizzle (T1): grid must be a multiple of 8.
__device__ __forceinline__ int swz8(){
  return (int)((blockIdx.x & 7) * (gridDim.x >> 3) + (blockIdx.x >> 3));
}

// CK-style async global->LDS, 16B per lane. LDS dest = uniform base + lane*16.
__device__ __forceinline__ void gll16(const u16* g, const uint4* l){
  __builtin_amdgcn_global_load_lds(
      reinterpret_cast<const __attribute__((address_space(1))) unsigned int*>(
          reinterpret_cast<uintptr_t>(g)),
      reinterpret_cast<__attribute__((address_space(3))) unsigned int*>(
          reinterpret_cast<uintptr_t>(l)),
      16, 0, 0);
}

// counted vmcnt wait (T4) + compiler-motion-safe raw barrier
#define WAITV(N) asm volatile("s_waitcnt vmcnt(" #N ")" ::: "memory")
#define BARRIER() do{ asm volatile("" ::: "memory"); \
                      __builtin_amdgcn_s_barrier(); \
                      asm volatile("" ::: "memory"); }while(0)

// ---------------- workspace layout ----------------
struct Lay {
  size_t z, c, zn, cn, Bt1h, Bt1l, Bt2h, Bt2l, cnt, fill, rowptr, deginv, csr,
         aggh, aggl, xh, xl, hh, hl, mh, partial, total;
};
static Lay mk_layout(int tc){
  Lay L; size_t o = 0;
  auto tk = [&](size_t b){ size_t p = o; o += ((b + 255) & ~(size_t)255); return p; };
  L.z       = tk((size_t)T_SEQ * HO * 4);
  L.c       = tk((size_t)T_SEQ * HO * 4);
  L.zn      = tk((size_t)T_SEQ * 4);
  L.cn      = tk((size_t)T_SEQ * 4);
  L.Bt1h    = tk((size_t)512 * 256 * 2);
  L.Bt1l    = tk((size_t)512 * 256 * 2);
  L.Bt2h    = tk((size_t)512 * 512 * 2);
  L.Bt2l    = tk((size_t)512 * 512 * 2);
  L.cnt     = tk((size_t)tc * NV * 4);
  L.fill    = tk((size_t)tc * NV * 4);
  L.rowptr  = tk((size_t)tc * (NV + 1) * 4);
  L.deginv  = tk((size_t)tc * NV * 4);
  L.csr     = tk((size_t)tc * NE * 4);
  L.aggh    = tk((size_t)tc * NV * CIN * 2);
  L.aggl    = tk((size_t)tc * NV * CIN * 2);
  L.xh      = tk((size_t)tc * NV * CIN * 2);
  L.xl      = tk((size_t)tc * NV * CIN * 2);
  L.hh      = tk((size_t)tc * NV * H2 * 2);
  L.hl      = tk((size_t)tc * NV * H2 * 2);
  L.mh      = tk((size_t)tc * NV * H2 * 4);
  L.partial = tk((size_t)tc * 128 * HO * 4);
  L.total = o; return L;
}

// ---------------- small kernels ----------------
__global__ void k_init_out(float* out){
  int i = threadIdx.x;
  if (i < 2) out[i] = 0.0f;
}

// B transposed + bf16-split: Bt1[n][k] (512x256), Bt2[n][k] (512x512)
__global__ void k_prep_Bt(const float* __restrict__ W1l, const float* __restrict__ W1r,
                          const float* __restrict__ W2l, const float* __restrict__ W2r,
                          u16* __restrict__ Bt1h, u16* __restrict__ Bt1l,
                          u16* __restrict__ Bt2h, u16* __restrict__ Bt2l){
  int i = blockIdx.x * 256 + threadIdx.x;
  if (i < 512 * 256){
    int n = i >> 8, k = i & 255;
    float v = (k < 128) ? W1l[k * 512 + n] : W1r[(k - 128) * 512 + n];
    u16 h = f2bf(v);
    Bt1h[i] = h; Bt1l[i] = f2bf(v - bf2f(h));
  } else {
    int j = i - 512 * 256;
    if (j < 512 * 512){
      int n = j >> 9, k = j & 511;
      float v = (n < 256) ? W2l[k * 256 + n] : W2r[k * 256 + (n - 256)];
      u16 h = f2bf(v);
      Bt2h[j] = h; Bt2l[j] = f2bf(v - bf2f(h));
    }
  }
}

__global__ void k_zero2(int* __restrict__ p, int* __restrict__ q, int n){
  int i = blockIdx.x * 256 + threadIdx.x;
  if (i < n){ p[i] = 0; q[i] = 0; }
}

__global__ void k_count(const int* __restrict__ ei, int t0, int tc, int* __restrict__ cnt){
  int i = blockIdx.x * 256 + threadIdx.x;
  if (i >= tc * NE) return;
  int tl = i >> 16, e = i & (NE - 1);
  int dst = ei[(size_t)(t0 + tl) * 2 * NE + NE + e];
  atomicAdd(&cnt[tl * NV + dst], 1);
}

__global__ void k_scan(const int* __restrict__ cnt, int* __restrict__ rowptr,
                       float* __restrict__ deginv){
  int tl = blockIdx.x, tid = threadIdx.x;
  __shared__ int s[256];
  int vals[16]; int sum = 0;
  const int* cb = cnt + tl * NV + tid * 16;
  #pragma unroll
  for (int i = 0; i < 16; i++){ vals[i] = cb[i]; sum += vals[i]; }
  s[tid] = sum; __syncthreads();
  for (int off = 1; off < 256; off <<= 1){
    int v = (tid >= off) ? s[tid - off] : 0;
    __syncthreads();
    s[tid] += v;
    __syncthreads();
  }
  int ex = s[tid] - sum;
  int* rp = rowptr + tl * (NV + 1) + tid * 16;
  float* dv = deginv + tl * NV + tid * 16;
  #pragma unroll
  for (int i = 0; i < 16; i++){
    rp[i] = ex; ex += vals[i];
    int d = vals[i] < 1 ? 1 : vals[i];
    dv[i] = 1.0f / (float)d;
  }
  if (tid == 255) rowptr[tl * (NV + 1) + NV] = ex;
}

__global__ void k_fill(const int* __restrict__ ei, int t0, int tc,
                       const int* __restrict__ rowptr, int* __restrict__ fill,
                       int* __restrict__ csr){
  int i = blockIdx.x * 256 + threadIdx.x;
  if (i >= tc * NE) return;
  int tl = i >> 16, e = i & (NE - 1);
  const int* eit = ei + (size_t)(t0 + tl) * 2 * NE;
  int src = eit[e], dst = eit[NE + e];
  int pos = atomicAdd(&fill[tl * NV + dst], 1);
  csr[tl * NE + rowptr[tl * (NV + 1) + dst] + pos] = src;
}

// conv1 aggregation + fused x-split: one wave per (t, v); lanes cover 128 ch as float2.
// XCD-swizzled: per-t x slice (2 MB) stays L2-resident per XCD.
__global__ __launch_bounds__(256) void k_agg1(const float* __restrict__ x, int t0, int tc,
                       const int* __restrict__ rowptr, const int* __restrict__ csr,
                       const float* __restrict__ deginv,
                       u16* __restrict__ aggh, u16* __restrict__ aggl,
                       u16* __restrict__ xh, u16* __restrict__ xl){
  int bid = swz8();
  int w = (bid * 256 + threadIdx.x) >> 6;
  int lane = threadIdx.x & 63;
  if (w >= tc * NV) return;
  int tl = w >> 12, v = w & (NV - 1);
  const float2* xt = (const float2*)(x + (size_t)(t0 + tl) * NV * CIN);
  int beg = rowptr[tl * (NV + 1) + v], end = rowptr[tl * (NV + 1) + v + 1];
  const int* cs = csr + tl * NE;
  float ax = 0.f, ay = 0.f;
  int j = beg;
  for (; j + 1 < end; j += 2){
    int s0 = cs[j], s1 = cs[j + 1];
    float2 x0 = xt[(size_t)s0 * 64 + lane];
    float2 x1 = xt[(size_t)s1 * 64 + lane];
    ax += x0.x + x1.x; ay += x0.y + x1.y;
  }
  if (j < end){
    int s0 = cs[j];
    float2 x0 = xt[(size_t)s0 * 64 + lane];
    ax += x0.x; ay += x0.y;
  }
  float di = deginv[tl * NV + v];
  float vx = ax * di, vy = ay * di;
  u16 hx = f2bf(vx), hy = f2bf(vy);
  u16 lx = f2bf(vx - bf2f(hx)), ly = f2bf(vy - bf2f(hy));
  ushort2 hv; hv.x = hx; hv.y = hy;
  ushort2 lv; lv.x = lx; lv.y = ly;
  ((ushort2*)aggh)[(size_t)w * 64 + lane] = hv;
  ((ushort2*)aggl)[(size_t)w * 64 + lane] = lv;
  // fused xsplit: this wave also splits node v's own x row (L2-hot from the gather)
  float2 xv = xt[(size_t)v * 64 + lane];
  u16 xhx = f2bf(xv.x), xhy = f2bf(xv.y);
  u16 xlx = f2bf(xv.x - bf2f(xhx)), xly = f2bf(xv.y - bf2f(xhy));
  ushort2 av; av.x = xhx; av.y = xhy;
  ushort2 bv; bv.x = xlx; bv.y = xly;
  ((ushort2*)xh)[(size_t)w * 64 + lane] = av;
  ((ushort2*)xl)[(size_t)w * 64 + lane] = bv;
}

// ---------------- split-bf16 MFMA GEMM (counted-vmcnt 2-barrier schedule) ----------------
// C[M x 512] = A @ B; A = [A0 | A1] split at ksplit (bf16 hi/lo planes, [M][lda]);
// B transposed: Bt[512][K] hi/lo. 3-term: Ah*Bh + Ah*Bl + Al*Bh.
// 128x128 block, 4 waves (2x2 of 64x64), BK=32, fragment-linear LDS filled by
// global_load_lds, double-buffered. Per K-step: STAGE(t+1); vmcnt(8); barrier;
// ds_read+MFMA(t); barrier. Prefetched loads stay in flight across the barrier
// (T4) instead of the vmcnt(0) drain of __syncthreads.
__global__ __launch_bounds__(256, 2) void k_gemm_mfma(
    const u16* __restrict__ Ah0, const u16* __restrict__ Al0,
    const u16* __restrict__ Ah1, const u16* __restrict__ Al1,
    int ksplit, int lda,
    const u16* __restrict__ Bh, const u16* __restrict__ Bl, int K,
    const float* __restrict__ bias, int mode,
    u16* __restrict__ OutH, u16* __restrict__ OutL, float* __restrict__ OutF)
{
  // 64 KB: per buffer (2048 uint4): Ah[0,512) Al[512,1024) Bh[1024,1536) Bl[1536,2048)
  __shared__ uint4 lds[4096];
  int tid = threadIdx.x;
  int bid = swz8();
  int bm = bid >> 2, bn = bid & 3;   // bn fastest within an XCD's contiguous chunk
  size_t row0 = (size_t)bm * 128;
  int col0 = bn * 128;
  int lane = tid & 63, wid = tid >> 6;
  int wm = wid >> 1, wn = wid & 1;
  int l15 = lane & 15, l4 = lane >> 4;

  // wave `wid` stages chunks {2*wid, 2*wid+1} (16 rows/cols each) of all 4 planes.
  size_t aoff[2], boff[2];
  int cslot[2];
  #pragma unroll
  for (int q = 0; q < 2; q++){
    int c = 2 * wid + q;
    aoff[q] = (row0 + c * 16 + l15) * (size_t)lda + (size_t)(l4 * 8);
    boff[q] = (size_t)(col0 + c * 16 + l15) * K + (size_t)(l4 * 8);
    cslot[q] = c * 64;
  }

#define STAGE(T) do { \
    int kk0_ = (T) << 5; \
    const u16* pAh_ = Ah0; const u16* pAl_ = Al0; int kA_ = kk0_; \
    if (kk0_ >= ksplit){ pAh_ = Ah1; pAl_ = Al1; kA_ = kk0_ - ksplit; } \
    int bb_ = ((T) & 1) << 11; \
    _Pragma("unroll") \
    for (int q = 0; q < 2; q++){ \
      gll16(pAh_ + aoff[q] + kA_, &lds[bb_ + cslot[q]]); \
      gll16(pAl_ + aoff[q] + kA_, &lds[bb_ + 512 + cslot[q]]); \
      gll16(Bh + boff[q] + kk0_, &lds[bb_ + 1024 + cslot[q]]); \
      gll16(Bl + boff[q] + kk0_, &lds[bb_ + 1536 + cslot[q]]); \
    } \
  } while (0)

  f32x4 zv = {0.f, 0.f, 0.f, 0.f};
  f32x4 acc[4][4];
  #pragma unroll
  for (int i = 0; i < 4; i++)
    #pragma unroll
    for (int j = 0; j < 4; j++) acc[i][j] = zv;

  STAGE(0);   // 8 loads in flight; iter 0's vmcnt(8)+barrier gates buf0 readiness

  int nt = K >> 5;
  for (int t = 0; t < nt; t++){
    if (t + 1 < nt){ STAGE(t + 1); WAITV(8); }  // my STAGE(t) landed; STAGE(t+1) stays in flight
    else          { WAITV(0); }
    BARRIER();                                   // all waves' STAGE(t) landed -> buf t complete
    int base = (t & 1) << 11;
    int abase = base + wm * 256;
    int bbase = base + 1024 + wn * 256;
    bf16x8 ah[4], al[4], bh[4], bl[4];
    #pragma unroll
    for (int f = 0; f < 4; f++){
      ah[f] = __builtin_bit_cast(bf16x8, lds[abase + f * 64 + lane]);
      al[f] = __builtin_bit_cast(bf16x8, lds[abase + 512 + f * 64 + lane]);
      bh[f] = __builtin_bit_cast(bf16x8, lds[bbase + f * 64 + lane]);
      bl[f] = __builtin_bit_cast(bf16x8, lds[bbase + 512 + f * 64 + lane]);
    }
    #pragma unroll
    for (int i = 0; i < 4; i++)
      #pragma unroll
      for (int j = 0; j < 4; j++){
        acc[i][j] = __builtin_amdgcn_mfma_f32_16x16x32_bf16(ah[i], bh[j], acc[i][j], 0, 0, 0);
        acc[i][j] = __builtin_amdgcn_mfma_f32_16x16x32_bf16(ah[i], bl[j], acc[i][j], 0, 0, 0);
        acc[i][j] = __builtin_amdgcn_mfma_f32_16x16x32_bf16(al[i], bh[j], acc[i][j], 0, 0, 0);
      }
    BARRIER();   // all waves done reading buf t -> next iter may overwrite it
  }
#undef STAGE

  // epilogue: C/D frag layout col=lane&15, row=(lane>>4)*4+reg
  #pragma unroll
  for (int i = 0; i < 4; i++){
    #pragma unroll
    for (int j = 0; j < 4; j++){
      int col = col0 + wn * 64 + j * 16 + l15;
      float bv = bias ? bias[col] : 0.f;
      #pragma unroll
      for (int r = 0; r < 4; r++){
        size_t row = row0 + wm * 64 + i * 16 + l4 * 4 + r;
        float v = acc[i][j][r] + bv;
        if (mode == 1){
          v = fmaxf(v, 0.f);
          u16 h = f2bf(v);
          u16 l = f2bf(v - bf2f(h));
          OutH[row * 512 + col] = h;
          OutL[row * 512 + col] = l;
        } else {
          OutF[row * 512 + col] = v;
        }
      }
    }
  }
}

// conv2 aggregation + finalize + per-block partial max-pool (mh fp32 [M][512]).
__global__ __launch_bounds__(256) void k_conv2agg(
    const float* __restrict__ mh, const int* __restrict__ rowptr,
    const int* __restrict__ csr, const float* __restrict__ deginv,
    const float* __restrict__ b2l, float* __restrict__ partial){
  int blk = swz8();
  int tl = blk >> 7, nb = blk & 127;
  int wid = threadIdx.x >> 6, lane = threadIdx.x & 63;
  const float4* m4 = (const float4*)mh;
  const int* rp = rowptr + tl * (NV + 1);
  const int* cs = csr + tl * NE;
  size_t tB = (size_t)tl * NV;
  float4 bb = ((const float4*)b2l)[lane];
  float4 vmax; vmax.x = NEG_FLT; vmax.y = NEG_FLT; vmax.z = NEG_FLT; vmax.w = NEG_FLT;
  int v0 = nb * 32 + wid * 8;
  for (int q = 0; q < 8; q++){
    int v = v0 + q;
    int beg = rp[v], end = rp[v + 1];
    float4 acc; acc.x = 0.f; acc.y = 0.f; acc.z = 0.f; acc.w = 0.f;
    int j = beg;
    for (; j + 1 < end; j += 2){
      int s0 = cs[j], s1 = cs[j + 1];
      float4 a0 = m4[(tB + s0) * 128 + lane];
      float4 a1 = m4[(tB + s1) * 128 + lane];
      acc.x += a0.x + a1.x; acc.y += a0.y + a1.y;
      acc.z += a0.z + a1.z; acc.w += a0.w + a1.w;
    }
    if (j < end){
      int s0 = cs[j];
      float4 a0 = m4[(tB + s0) * 128 + lane];
      acc.x += a0.x; acc.y += a0.y; acc.z += a0.z; acc.w += a0.w;
    }
    float di = deginv[tl * NV + v];
    float4 hr = m4[(tB + v) * 128 + 64 + lane];
    float4 val;
    val.x = acc.x * di + bb.x + hr.x;
    val.y = acc.y * di + bb.y + hr.y;
    val.z = acc.z * di + bb.z + hr.z;
    val.w = acc.w * di + bb.w + hr.w;
    vmax.x = fmaxf(vmax.x, val.x); vmax.y = fmaxf(vmax.y, val.y);
    vmax.z = fmaxf(vmax.z, val.z); vmax.w = fmaxf(vmax.w, val.w);
  }
  __shared__ float4 sm[4][64];
  sm[wid][lane] = vmax;
  __syncthreads();
  if (wid == 0){
    float4 a = sm[0][lane], b = sm[1][lane], c = sm[2][lane], d = sm[3][lane];
    float4 r;
    r.x = fmaxf(fmaxf(a.x, b.x), fmaxf(c.x, d.x));
    r.y = fmaxf(fmaxf(a.y, b.y), fmaxf(c.y, d.y));
    r.z = fmaxf(fmaxf(a.z, b.z), fmaxf(c.z, d.z));
    r.w = fmaxf(fmaxf(a.w, b.w), fmaxf(c.w, d.w));
    ((float4*)partial)[((size_t)(tl * 128 + nb)) * 64 + lane] = r;
  }
}

// parallel max-pool: grid = tc*4 blocks; block (tl, cg) reduces 128 partials for 64 ch.
__global__ void k_pool(const float* __restrict__ partial, int t0,
                       float* __restrict__ z){
  int blk = blockIdx.x;
  int tl = blk >> 2, cg = blk & 3;
  int tid = threadIdx.x;
  int c = cg * 64 + (tid & 63);
  int grp = tid >> 6;
  float m = NEG_FLT;
  for (int b = grp; b < 128; b += 4)
    m = fmaxf(m, partial[((size_t)(tl * 128 + b)) * HO + c]);
  __shared__ float s[4][64];
  s[grp][tid & 63] = m;
  __syncthreads();
  if (grp == 0){
    m = fmaxf(fmaxf(s[0][tid], s[1][tid]), fmaxf(s[2][tid], s[3][tid]));
    z[(t0 + tl) * HO + c] = m;
  }
}

__global__ void k_gru(const float* __restrict__ z, const float* __restrict__ Wih,
                      const float* __restrict__ bih, const float* __restrict__ bhh,
                      float* __restrict__ c, float* __restrict__ cn, float* __restrict__ out){
  int s0 = blockIdx.x, j = threadIdx.x;
  __shared__ float zs[256];
  __shared__ float ss[256];
  zs[j] = z[s0 * HO + j];
  __syncthreads();
  const float* wr = Wih + (size_t)j * HO;
  const float* wu = Wih + (size_t)(HO + j) * HO;
  const float* wn = Wih + (size_t)(2 * HO + j) * HO;
  float gr = bih[j], gu = bih[HO + j], gn = bih[2 * HO + j];
  for (int k = 0; k < HO; k++){
    float zv = zs[k];
    gr = fmaf(zv, wr[k], gr);
    gu = fmaf(zv, wu[k], gu);
    gn = fmaf(zv, wn[k], gn);
  }
  float r = 1.f / (1.f + expf(-(gr + bhh[j])));
  float u = 1.f / (1.f + expf(-(gu + bhh[HO + j])));
  float n = tanhf(gn + r * bhh[2 * HO + j]);
  float cv = (1.f - u) * n;
  c[s0 * HO + j] = cv;
  if (s0 < 44) out[2 + s0 * HO + j] = cv;
  ss[j] = cv * cv; __syncthreads();
  for (int off = 128; off > 0; off >>= 1){
    if (j < off) ss[j] += ss[j + off];
    __syncthreads();
  }
  if (j == 0) cn[s0] = sqrtf(ss[0]);
}

// CPC: z-norms computed inline alongside the dot (same loads), cn from k_gru.
__global__ void k_cpc(const float* __restrict__ z, const float* __restrict__ c,
                      const float* __restrict__ cn, float* __restrict__ out){
  int tt = blockIdx.x;
  int ts = 8 + tt;
  int tid = threadIdx.x;
  __shared__ float ct[256];
  __shared__ float tot[32];
  ct[tid] = c[ts * HO + tid];
  __syncthreads();
  int g = tid >> 3, r = tid & 7;
  int i = g >> 3, j = g & 7;
  int idx = ts + ((j == 0) ? (i + 1) : (i + j + 10));
  const float* zr = z + idx * HO;
  float s = 0.f, nz = 0.f;
  for (int k = r; k < HO; k += 8){
    float zv = zr[k];
    s = fmaf(zv, ct[k], s);
    nz = fmaf(zv, zv, nz);
  }
  s += __shfl_down(s, 4, 8);  nz += __shfl_down(nz, 4, 8);
  s += __shfl_down(s, 2, 8);  nz += __shfl_down(nz, 2, 8);
  s += __shfl_down(s, 1, 8);  nz += __shfl_down(nz, 1, 8);
  if (r == 0){
    float den = fmaxf(sqrtf(nz), 1e-8f) * fmaxf(cn[ts], 1e-8f);
    tot[g] = s / den;
  }
  __syncthreads();
  if (tid < 4){
    const float* tr = tot + tid * 8;
    float m = tr[0];
    for (int q = 1; q < 8; q++) m = fmaxf(m, tr[q]);
    float se = 0.f;
    for (int q = 0; q < 8; q++) se += expf(tr[q] - m);
    float lse = m + logf(se);
    float nce = (lse - tr[0]) * (1.0f / 144.0f);
    float corr = (tr[0] == m) ? (1.0f / 144.0f) : 0.f;
    atomicAdd(&out[0], nce);
    atomicAdd(&out[1], corr);
  }
}

// ---------------- launch ----------------
extern "C" void kernel_launch(void* const* d_in, const int* in_sizes, int n_in,
                              void* d_out, int out_size, void* d_ws, size_t ws_size,
                              hipStream_t stream){
  const float* x   = (const float*)d_in[0];
  const int*   ei  = (const int*)  d_in[1];
  const float* W1l = (const float*)d_in[2];
  const float* b1l = (const float*)d_in[3];
  const float* W1r = (const float*)d_in[4];
  const float* W2l = (const float*)d_in[5];
  const float* b2l = (const float*)d_in[6];
  const float* W2r = (const float*)d_in[7];
  const float* Wih = (const float*)d_in[8];
  const float* bih = (const float*)d_in[10];
  const float* bhh = (const float*)d_in[11];
  float* out = (float*)d_out;

  int tc = 64;
  while (tc > 1 && mk_layout(tc).total > ws_size) tc >>= 1;
  Lay L = mk_layout(tc);
  char* w = (char*)d_ws;
  float* zB   = (float*)(w + L.z);
  float* cB   = (float*)(w + L.c);
  float* cnB  = (float*)(w + L.cn);
  u16*   Bt1h = (u16*)  (w + L.Bt1h);
  u16*   Bt1l = (u16*)  (w + L.Bt1l);
  u16*   Bt2h = (u16*)  (w + L.Bt2h);
  u16*   Bt2l = (u16*)  (w + L.Bt2l);
  int*   cnt  = (int*)  (w + L.cnt);
  int*   fill = (int*)  (w + L.fill);
  int*   rp   = (int*)  (w + L.rowptr);
  float* dinv = (float*)(w + L.deginv);
  int*   csr  = (int*)  (w + L.csr);
  u16*   aggh = (u16*)  (w + L.aggh);
  u16*   aggl = (u16*)  (w + L.aggl);
  u16*   xh   = (u16*)  (w + L.xh);
  u16*   xl   = (u16*)  (w + L.xl);
  u16*   hh   = (u16*)  (w + L.hh);
  u16*   hl   = (u16*)  (w + L.hl);
  float* mhB  = (float*)(w + L.mh);
  float* part = (float*)(w + L.partial);

  hipLaunchKernelGGL(k_init_out, dim3(1), dim3(64), 0, stream, out);
  hipLaunchKernelGGL(k_prep_Bt, dim3(1536), dim3(256), 0, stream,
                     W1l, W1r, W2l, W2r, Bt1h, Bt1l, Bt2h, Bt2l);

  for (int t0 = 0; t0 < T_SEQ; t0 += tc){
    int nE = tc * NE;
    int M = tc * NV;
    hipLaunchKernelGGL(k_zero2, dim3((tc * NV + 255) / 256), dim3(256), 0, stream,
                       cnt, fill, tc * NV);
    hipLaunchKernelGGL(k_count, dim3((nE + 255) / 256), dim3(256), 0, stream, ei, t0, tc, cnt);
    hipLaunchKernelGGL(k_scan, dim3(tc), dim3(256), 0, stream, cnt, rp, dinv);
    hipLaunchKernelGGL(k_fill, dim3((nE + 255) / 256), dim3(256), 0, stream, ei, t0, tc, rp, fill, csr);
    hipLaunchKernelGGL(k_agg1, dim3(tc * NV / 4), dim3(256), 0, stream,
                       x, t0, tc, rp, csr, dinv, aggh, aggl, xh, xl);
    // conv1: h = relu([agg | x] @ B1 + b1l) -> bf16 hi/lo planes
    hipLaunchKernelGGL(k_gemm_mfma, dim3((M / 128) * 4), dim3(256), 0, stream,
                       aggh, aggl, xh, xl, 128, CIN,
                       Bt1h, Bt1l, 256, b1l, 1, hh, hl, (float*)nullptr);
    // conv2: mh = h @ B2 -> fp32
    hipLaunchKernelGGL(k_gemm_mfma, dim3((M / 128) * 4), dim3(256), 0, stream,
                       hh, hl, hh, hl, 1 << 30, H2,
                       Bt2h, Bt2l, 512, (const float*)nullptr, 0,
                       (u16*)nullptr, (u16*)nullptr, mhB);
    hipLaunchKernelGGL(k_conv2agg, dim3(tc * 128), dim3(256), 0, stream,
                       mhB, rp, csr, dinv, b2l, part);
    hipLaunchKernelGGL(k_pool, dim3(tc * 4), dim3(256), 0, stream, part, t0, zB);
  }

  hipLaunchKernelGGL(k_gru, dim3(T_SEQ), dim3(256), 0, stream, zB, Wih, bih, bhh, cB, cnB, out);
  hipLaunchKernelGGL(k_cpc, dim3(36), dim3(256), 0, stream, zB, cB, cnB, out);
  (void)in_sizes; (void)n_in; (void)out_size;
}